// Round 4
// baseline (1269.072 us; speedup 1.0000x reference)
//
#include <hip/hip_runtime.h>
#include <hip/hip_bf16.h>

// ---------------------------------------------------------------------------
// Problem constants
// ---------------------------------------------------------------------------
#define BB   8
#define CIN  256
#define CHN  256
#define HH   128
#define WWD  128
#define HW   (HH * WWD)        // 16384
#define GRP_ELEMS ((size_t)32 * HW)   // 524288

// borderline-label flag thresholds.
#define FLAG_DL   4e-3f
#define FLAG_GAP  1.5e-3f

// ws BYTE layout. First MEMSET_BYTES (+8K zero page) are zeroed each call.
#define BO_DSUM1   0        // double[128] (sum[64], sumsq[64]) head1
#define BO_DSUM2   1024     // double[128] head2 (contiguous after head1)
#define BO_FSTAT1  2048     // float[128] (mu[64], rstd[64]) head1
#define BO_FSTAT2  2560     // head2 (contiguous)
#define BO_DSTAT1  3072     // double[128] head1
#define BO_DSTAT2  4096     // head2 (contiguous)
#define BO_MEAN    5120     // float[32]
#define BO_CNT     5248     // float[8]
#define BO_TOPK    5280     // float[32]
#define BO_FLAGC   5408     // int (worklist counter)
#define MEMSET_BYTES 8192
#define BO_WL      8192     // int[32768] worklist (first 8KB doubles as conv
                            // zero page: conv runs before decode writes wl)
#define WLCAP      32768

// MFMA-path big buffers (bytes)
#define XP_OFF    139264ull
#define XP_BYTES  67108864ull                  // 8*128*8*128*32 fp16 (ushort)
#define HB_OFF    (XP_OFF + XP_BYTES)
#define HB_BYTES  134217728ull                 // 8*256*16384 fp32
#define WH_OFF    (HB_OFF + HB_BYTES)
#define WT1_ELEMS 589824                       // per-head Whh/Whl ushorts; also Wt32 floats/head
#define WH2_BYTES 2359296ull                   // 2 heads * 9*8*256*32 fp16
#define WL2_OFF   (WH_OFF + WH2_BYTES)
#define WT32_OFF  (WL2_OFF + WH2_BYTES)
#define WT32_BYTES 4718592ull                  // 2 heads * 9*256*256 fp32
#define HB2_OFF   (WT32_OFF + WT32_BYTES)
#define NEED_B    (WT32_OFF + WT32_BYTES)      // sequential-conv path
#define NEED_A    (HB2_OFF + HB_BYTES)         // merged-conv path (hb2 live)

// d_out flat offsets (outputs concatenated in return order, all float)
#define O_DMG   0
#define O_CORN  131072
#define O_PIX   393216
#define O_LAB   917504
#define O_MEAN  1048576
#define O_TOPK  1048608
#define O_AGG   1048640
#define O_ALAB  1048672

typedef __attribute__((ext_vector_type(8))) _Float16 f16x8;
typedef __attribute__((ext_vector_type(4))) float f32x4;

__device__ inline ushort f2h(float f) {
    _Float16 h = (_Float16)f;
    union { _Float16 h; ushort u; } c; c.h = h; return c.u;
}
__device__ inline float h2f(ushort u) {
    union { ushort u; _Float16 h; } c; c.u = u; return (float)c.h;
}

__device__ inline void store4v(float* p, float a, float b, float c, float d) {
    *(float4*)p = make_float4(a, b, c, d);
}
__device__ inline void store4v(__hip_bfloat16* p, float a, float b, float c, float d) {
    p[0] = __float2bfloat16(a); p[1] = __float2bfloat16(b);
    p[2] = __float2bfloat16(c); p[3] = __float2bfloat16(d);
}
__device__ inline float ldv(const float* p) { return *p; }
__device__ inline float ldv(const __hip_bfloat16* p) { return __bfloat162float(*p); }

// ===========================================================================
// MFMA PATH (fp16, 2-product: h = fp16(x) * (wh + wl))
// ===========================================================================

// Pack x [b][ci][y][x] fp32 -> Xh [b][y][cc][x][ci32] fp16. grid 8192.
__global__ __launch_bounds__(256) void pack_x_f16(
    const float* __restrict__ x, ushort* __restrict__ Xh)
{
    int bid = blockIdx.x;
    int cc = bid & 7;
    int y  = (bid >> 3) & 127;
    int b  = bid >> 10;
    __shared__ ushort tile[32][137];
    const int tid = threadIdx.x;
    for (int i = tid; i < 1024; i += 256) {
        int ci = i >> 5;            // 0..31
        int x4 = (i & 31) << 2;     // 0..124
        float4 v = *(const float4*)&x[(((size_t)b * 256 + cc * 32 + ci) * 128 + y) * 128 + x4];
        tile[ci][x4 + 0] = f2h(v.x);
        tile[ci][x4 + 1] = f2h(v.y);
        tile[ci][x4 + 2] = f2h(v.z);
        tile[ci][x4 + 3] = f2h(v.w);
    }
    __syncthreads();
    ushort* dst = Xh + ((((size_t)b * 128 + y) * 8 + cc) << 12);
    for (int i = tid; i < 512; i += 256) {
        int xx  = i >> 2;
        int ci0 = (i & 3) << 3;
        ushort tmp[8];
#pragma unroll
        for (int j = 0; j < 8; j++) tmp[j] = tile[ci0 + j][xx];
        *(uint4*)&dst[i << 3] = *(uint4*)tmp;
    }
}

// w [co][ci][3][3] fp32 -> Whh/Whl fp16 hi/lo, SWIZZLED into MFMA B-fragment
// order. Wt32 [tap][ci][co] fp32 for the fp64 fixup (LDS-transposed).
__global__ __launch_bounds__(256) void transpose_w(
    const float* __restrict__ w, ushort* __restrict__ Whh,
    ushort* __restrict__ Whl, float* __restrict__ Wt32)
{
    __shared__ float lt[8][33];
    int idx = blockIdx.x * 256 + threadIdx.x;   // < 589824
    int tap = idx >> 16;
    int rem = idx & 65535;
    int cc  = rem >> 13;
    int co  = (rem >> 5) & 255;
    int ci5 = rem & 31;
    int ci  = cc * 32 + ci5;
    float v = w[((size_t)co * 256 + ci) * 9 + tap];
    ushort h = f2h(v);
    int sidx = (((tap * 8 + cc) * 16 + (co >> 4)) << 9)
             + (((co & 15) + ((ci5 >> 3) << 4)) << 3) + (ci5 & 7);
    Whh[sidx] = h;
    Whl[sidx] = f2h(v - h2f(h));
    lt[threadIdx.x >> 5][ci5] = v;
    __syncthreads();
    int co_base = (blockIdx.x * 8) & 255;
    int ci5w = threadIdx.x >> 3;
    int j    = threadIdx.x & 7;
    Wt32[((size_t)tap * 256 + cc * 32 + ci5w) * 256 + co_base + j] = lt[j][ci5w];
}

// ---------------------------------------------------------------------------
// global_load_lds helpers (direct HBM/L2 -> LDS DMA, 16B per lane)
// ---------------------------------------------------------------------------
__device__ __forceinline__ void gld16(const void* g, void* l)
{
    __builtin_amdgcn_global_load_lds(
        (const __attribute__((address_space(1))) void*)g,
        (__attribute__((address_space(3))) void*)l, 16, 0, 0);
}

// ======================= 8-wave (512-thread) conv ==========================
// Stage one B slice (tap,cc), BOTH heads, full 256 co: 2 heads x (16K hi +
// 16K lo) = 64 KB, 8 gld16 per thread (uniform).
__device__ __forceinline__ void issue_b8(
    const ushort* __restrict__ Whh, const ushort* __restrict__ Whl,
    ushort* dst, int u, int tid, int wb8)
{
    const int su  = u / 3;               // step index (ky*8+cc)
    const int kxu = u - su * 3;
    const int tap = ((su >> 3) * 3) + kxu;
    const int cc  = su & 7;
    const size_t sbase = ((size_t)((tap * 8 + cc) * 16)) << 9;   // 8192 ushorts
#pragma unroll
    for (int h = 0; h < 2; h++) {
        const ushort* s0 = Whh + h * WT1_ELEMS + sbase;
        const ushort* s1 = Whl + h * WT1_ELEMS + sbase;
        ushort* d = dst + h * 16384;
#pragma unroll
        for (int c = 0; c < 2; c++) {
            gld16(s0 + (size_t)(c * 512 + tid) * 8, d + (size_t)(c * 512 + wb8) * 8);
            gld16(s1 + (size_t)(c * 512 + tid) * 8, d + 8192 + (size_t)(c * 512 + wb8) * 8);
        }
    }
}

// Stage one A tile (row, cc): 128 xg x 32 ci fp16 = 8 KB, 1 gld16 per thread.
// Linear LDS dest; bank-conflict swizzle on the GLOBAL source address here
// and on the ds_read offset in the compute loop (rule #21).
__device__ __forceinline__ void issue_a8(
    const ushort* __restrict__ Xh, const ushort* __restrict__ zb,
    ushort* dst, int b, int y, int sn, int tid, int wb8)
{
    const int kyn = sn >> 3, ccn = sn & 7;
    const int rown = y + kyn - 1;
    const bool rv = (unsigned)rown < 128u;
    const ushort* base = rv ? (Xh + ((((size_t)b * 128 + rown) * 8 + ccn) << 12)) : zb;
    int xi  = (tid + 4) >> 2;                  // 1..128
    int q   = (tid & 3) ^ ((xi >> 1) & 3);     // source-side swizzle
    int off = rv ? ((xi - 1) * 32 + q * 8) : (tid * 8);
    gld16(base + off, dst + 32 + (size_t)wb8 * 8);
}

// Conv3x3 via 16x16x32 fp16 MFMA, 2 products. 8-wave restructure:
// block = 512 threads, 128px x 256co x BOTH heads (A tile shared by heads).
// Wave wv: head = wv>>2, co-quarter q4 = wv&3; per wave 128px x 64co (f=8).
// LDS reads/FLOP cut 1.5x vs 4-wave version; A staging/fetch cut 4x.
// 72-phase pipeline, counted vmcnt {9,9,8}; LDS 145 KB -> 1 block/CU,
// 2 waves/SIMD (m201/HK regime). grid (1024).
__global__ __launch_bounds__(512, 2) void conv3x3_mfma8(
    const ushort* __restrict__ Xh, const ushort* __restrict__ Whh,
    const ushort* __restrict__ Whl, const ushort* __restrict__ zb,
    float* __restrict__ hb1, float* __restrict__ hb2,
    double* __restrict__ sums)
{
    __shared__ ushort a_lds[2][4160];       // [buf][row(130) * 32], 64 B rows
    __shared__ ushort b_lds[2][2][16384];   // [buf][head][hi 8192 | lo 8192]
    __shared__ float sred[32];              // [head][8 sum | 8 sq]

    const int bxr = blockIdx.x;
    const int y   = bxr >> 3;
    const int b   = bxr & 7;
    const int tid  = threadIdx.x;
    const int lane = tid & 63;
    const int wb8  = tid & 448;          // wave base (uniform per wave)
    const int wv   = tid >> 6;
    const int head = wv >> 2;
    const int q4   = wv & 3;             // co quarter: co0_w = q4*64
    const int m = lane & 15;
    const int q = lane >> 4;

    if (tid < 32) sred[tid] = 0.f;
    // zero halo rows (xi=0,129) of both A buffers: 4 rows x 64 B
    if (tid < 16) {
        int tg = tid >> 2, p4 = tid & 3;
        ushort* r = &a_lds[tg >> 1][(tg & 1) ? (129 * 32) : 0];
        *(uint4*)(r + p4 * 8) = make_uint4(0u, 0u, 0u, 0u);
    }

    f32x4 acc[8][4];
#pragma unroll
    for (int f = 0; f < 8; f++)
#pragma unroll
        for (int g = 0; g < 4; g++) acc[f][g] = (f32x4){0.f, 0.f, 0.f, 0.f};

    // prologue: A(0) -> buf0, B(0,kx0) -> buf0; drain LDS init writes
    issue_a8(Xh, zb, a_lds[0], b, y, 0, tid, wb8);
    issue_b8(Whh, Whl, &b_lds[0][0][0], 0, tid, wb8);
    asm volatile("s_waitcnt lgkmcnt(0)" ::: "memory");

    for (int s = 0; s < 24; s++) {
        const ushort* acur = a_lds[s & 1];
#pragma unroll
        for (int kx = 0; kx < 3; kx++) {
            const int t = 3 * s + kx;
            asm volatile("" ::: "memory");
            __builtin_amdgcn_s_barrier();           // TOP: write-safety
            {   // prefetch B(t+1) (dummy wrap at tail keeps vmcnt uniform)
                int u = t + 1;
                int ub = u & 1;                     // from UNCLAMPED u
                if (u > 71) u = 71;
                issue_b8(Whh, Whl, &b_lds[ub][0][0], u, tid, wb8);
            }
            if (kx == 0) {                          // prefetch A(s+1)
                int sn = s + 1;
                int ab = sn & 1;                    // from UNCLAMPED sn
                if (sn > 23) sn = 23;
                issue_a8(Xh, zb, a_lds[ab], b, y, sn, tid, wb8);
            }
            // counted waits: keep {B(t+1)=8 [, A(s+1)=1]} in flight.
            // kx==2 drains the pending A early (it's older than B(t)).
            if (kx == 2) asm volatile("s_waitcnt vmcnt(8)" ::: "memory");
            else         asm volatile("s_waitcnt vmcnt(9)" ::: "memory");
            __builtin_amdgcn_s_barrier();           // MID: read-safety
            asm volatile("" ::: "memory");

            const ushort* bbH = &b_lds[t & 1][head][0];
            f16x8 ah[8];
#pragma unroll
            for (int f = 0; f < 8; f++) {
                int row = f * 16 + kx + m;
                ah[f] = *(const f16x8*)(acur + row * 32
                        + ((q ^ ((row >> 1) & 3)) << 3));   // read-side swizzle
            }
            __builtin_amdgcn_s_setprio(1);
#pragma unroll
            for (int g = 0; g < 4; g++) {
                int off = ((q4 * 4 + g) << 9) + (lane << 3);
                f16x8 bh = *(const f16x8*)&bbH[off];
                f16x8 bl = *(const f16x8*)&bbH[8192 + off];
#pragma unroll
                for (int f = 0; f < 8; f++)
                    acc[f][g] = __builtin_amdgcn_mfma_f32_16x16x32_f16(ah[f], bh, acc[f][g], 0, 0, 0);
#pragma unroll
                for (int f = 0; f < 8; f++)
                    acc[f][g] = __builtin_amdgcn_mfma_f32_16x16x32_f16(ah[f], bl, acc[f][g], 0, 0, 0);
            }
            __builtin_amdgcn_s_setprio(0);
        }
    }

    float* ho = head ? hb2 : hb1;
    float s0 = 0.f, q0 = 0.f, s1 = 0.f, q1 = 0.f;
#pragma unroll
    for (int f = 0; f < 8; f++) {
#pragma unroll
        for (int g = 0; g < 4; g++) {
            f32x4 v = acc[f][g];
            float a = v.x + v.y + v.z + v.w;
            float qq = v.x * v.x + v.y * v.y + v.z * v.z + v.w * v.w;
            if (g < 2) { s0 += a; q0 += qq; } else { s1 += a; q1 += qq; }
            int px = f * 16 + q * 4;
            int co = q4 * 64 + g * 16 + m;
            *(f32x4*)&ho[((size_t)(b * 256 + co) * 128 + y) * 128 + px] = v;
        }
    }
    int gl = q4 * 2;
    atomicAdd(&sred[head * 16 + gl],     s0);
    atomicAdd(&sred[head * 16 + gl + 1], s1);
    atomicAdd(&sred[head * 16 + 8 + gl],     q0);
    atomicAdd(&sred[head * 16 + 8 + gl + 1], q1);
    __syncthreads();
    if (tid < 32) {
        int h = tid >> 4, r = tid & 15;
        if (r < 8) atomicAdd(&sums[h * 128 + b * 8 + r], (double)sred[h * 16 + r]);
        else       atomicAdd(&sums[h * 128 + 64 + b * 8 + (r - 8)],
                             (double)sred[h * 16 + r]);
    }
}

// ======================= 4-wave conv (NEED_B fallback) =====================
__device__ __forceinline__ void issue_b_slice(
    const ushort* __restrict__ Whh, const ushort* __restrict__ Whl,
    ushort* dst, int u, int co0, int tid, int wb)
{
    const int su  = u / 3;
    const int kxu = u - su * 3;
    const int tap = ((su >> 3) * 3) + kxu;
    const int cc  = su & 7;
    const size_t sbase = ((size_t)((tap * 8 + cc) * 16 + (co0 >> 4)) << 9);
    const ushort* s0 = Whh + sbase;
    const ushort* s1 = Whl + sbase;
#pragma unroll
    for (int k = 0; k < 2; k++)
        gld16(s0 + (k * 256 + tid) * 8, dst + (size_t)(k * 256 + wb) * 8);
#pragma unroll
    for (int k = 0; k < 2; k++)
        gld16(s1 + (k * 256 + tid) * 8, dst + 4096 + (size_t)(k * 256 + wb) * 8);
}

__device__ __forceinline__ void issue_a_slice(
    const ushort* __restrict__ Xh, const ushort* __restrict__ zb,
    ushort* dst, int b, int y, int sn, int tid, int wb)
{
    const int kyn = sn >> 3, ccn = sn & 7;
    const int rown = y + kyn - 1;
    const bool rv = (unsigned)rown < 128u;
    const ushort* base = rv ? (Xh + ((((size_t)b * 128 + rown) * 8 + ccn) << 12)) : zb;
#pragma unroll
    for (int k = 0; k < 2; k++) {
        int idx = k * 256 + tid;
        int xi  = (idx + 4) >> 2;
        int q   = (idx & 3) ^ ((xi >> 1) & 3);
        int off = rv ? ((xi - 1) * 32 + q * 8) : (idx * 8);
        gld16(base + off, dst + 32 + (size_t)(k * 256 + wb) * 8);
    }
}

__global__ __launch_bounds__(256, 3) void conv3x3_mfma4(
    const ushort* __restrict__ Xh, const ushort* __restrict__ Whh,
    const ushort* __restrict__ Whl, const ushort* __restrict__ zb,
    float* __restrict__ hout, double* __restrict__ sums, int head)
{
    __shared__ ushort a_lds[2][4160];
    __shared__ ushort b_lds[2][8192];
    __shared__ float sred[8];

    const int bxr = blockIdx.x;
    const int y   = bxr >> 3;
    const int b   = bxr & 7;
    const int co0 = blockIdx.y << 7;
    const ushort* WhhH = Whh + head * WT1_ELEMS;
    const ushort* WhlH = Whl + head * WT1_ELEMS;
    double* sumsH = sums + head * 128;

    const int tid  = threadIdx.x;
    const int lane = tid & 63;
    const int wb   = tid & 192;
    const int wv   = tid >> 6;
    const int m = lane & 15;
    const int q = lane >> 4;
    const int wpx = (wv & 1) << 6;
    const int wco = (wv >> 1) << 6;
    const int g0  = wco >> 4;

    if (tid < 8) sred[tid] = 0.f;
    if (tid < 16) {
        int tg = tid >> 2, p4 = tid & 3;
        ushort* r = &a_lds[tg >> 1][(tg & 1) ? (129 * 32) : 0];
        *(uint4*)(r + p4 * 8) = make_uint4(0u, 0u, 0u, 0u);
    }

    f32x4 acc[4][4];
#pragma unroll
    for (int f = 0; f < 4; f++)
#pragma unroll
        for (int g = 0; g < 4; g++) acc[f][g] = (f32x4){0.f, 0.f, 0.f, 0.f};

    issue_a_slice(Xh, zb, a_lds[0], b, y, 0, tid, wb);
    issue_b_slice(WhhH, WhlH, b_lds[0], 0, co0, tid, wb);
    asm volatile("s_waitcnt lgkmcnt(0)" ::: "memory");

    for (int s = 0; s < 24; s++) {
        const ushort* acur = a_lds[s & 1];
#pragma unroll
        for (int kx = 0; kx < 3; kx++) {
            const int t = 3 * s + kx;
            asm volatile("" ::: "memory");
            __builtin_amdgcn_s_barrier();
            {
                int u = t + 1;
                int ub = u & 1;
                if (u > 71) u = 71;
                issue_b_slice(WhhH, WhlH, b_lds[ub], u, co0, tid, wb);
            }
            if (kx == 0) {
                int sn = s + 1;
                int ab = sn & 1;
                if (sn > 23) sn = 23;
                issue_a_slice(Xh, zb, a_lds[ab], b, y, sn, tid, wb);
            }
            if (kx == 2) asm volatile("s_waitcnt vmcnt(4)" ::: "memory");
            else         asm volatile("s_waitcnt vmcnt(6)" ::: "memory");
            __builtin_amdgcn_s_barrier();
            asm volatile("" ::: "memory");

            const ushort* bb = b_lds[t & 1];
            f16x8 ah[4], bh[4], bl[4];
#pragma unroll
            for (int f = 0; f < 4; f++) {
                int row = wpx + f * 16 + kx + m;
                ah[f] = *(const f16x8*)(acur + row * 32
                        + ((q ^ ((row >> 1) & 3)) << 3));
            }
#pragma unroll
            for (int g = 0; g < 4; g++) {
                int off = ((g0 + g) << 9) + (lane << 3);
                bh[g] = *(const f16x8*)&bb[off];
                bl[g] = *(const f16x8*)&bb[4096 + off];
            }
            __builtin_amdgcn_s_setprio(1);
#pragma unroll
            for (int f = 0; f < 4; f++)
#pragma unroll
                for (int g = 0; g < 4; g++)
                    acc[f][g] = __builtin_amdgcn_mfma_f32_16x16x32_f16(ah[f], bh[g], acc[f][g], 0, 0, 0);
#pragma unroll
            for (int f = 0; f < 4; f++)
#pragma unroll
                for (int g = 0; g < 4; g++)
                    acc[f][g] = __builtin_amdgcn_mfma_f32_16x16x32_f16(ah[f], bl[g], acc[f][g], 0, 0, 0);
            __builtin_amdgcn_s_setprio(0);
        }
    }

    float s0 = 0.f, q0 = 0.f, s1 = 0.f, q1 = 0.f;
#pragma unroll
    for (int f = 0; f < 4; f++) {
#pragma unroll
        for (int g = 0; g < 4; g++) {
            f32x4 v = acc[f][g];
            float a = v.x + v.y + v.z + v.w;
            float qq = v.x * v.x + v.y * v.y + v.z * v.z + v.w * v.w;
            if (g < 2) { s0 += a; q0 += qq; } else { s1 += a; q1 += qq; }
            int px = wpx + f * 16 + q * 4;
            int co = co0 + wco + g * 16 + m;
            *(f32x4*)&hout[((size_t)(b * 256 + co) * 128 + y) * 128 + px] = v;
        }
    }
    int gl = wco >> 5;
    atomicAdd(&sred[gl],     s0);
    atomicAdd(&sred[gl + 1], s1);
    atomicAdd(&sred[4 + gl],     q0);
    atomicAdd(&sred[4 + gl + 1], q1);
    __syncthreads();
    if (tid < 4) atomicAdd(&sumsH[b * 8 + (co0 >> 5) + tid], (double)sred[tid]);
    else if (tid < 8) atomicAdd(&sumsH[64 + b * 8 + (co0 >> 5) + tid - 4], (double)sred[tid]);
}

// ===========================================================================
// fp32 fallback conv (kept for safety; not expected to run)
// ===========================================================================
template <typename HT>
__global__ __launch_bounds__(256) void conv3x3_gn_stats(
    const float* __restrict__ x, const float* __restrict__ w,
    HT* __restrict__ hout, double* __restrict__ sums)
{
    __shared__ float in_lds[8][3][132];
    __shared__ float w_lds[8][9][68];
    __shared__ float sred[2], qred[2];

    const int bx  = blockIdx.x;
    const int y   = bx & (HH - 1);
    const int b   = bx >> 7;
    const int co0 = blockIdx.y << 6;
    const int tid = threadIdx.x;
    if (tid < 2) { sred[tid] = 0.f; qred[tid] = 0.f; }
    const int tco = (tid & 15) << 2;
    const int tox = (tid >> 4) << 3;

    float acc[4][8];
#pragma unroll
    for (int i = 0; i < 4; i++)
#pragma unroll
        for (int j = 0; j < 8; j++) acc[i][j] = 0.f;

    const float* xb = x + (size_t)b * CIN * HW;
    for (int c0 = 0; c0 < CIN; c0 += 8) {
        __syncthreads();
        for (int i = tid; i < 8 * 3 * 130; i += 256) {
            int ci  = i / 390;
            int rem = i - ci * 390;
            int r   = rem / 130;
            int cx  = rem - r * 130;
            int gy  = y + r - 1;
            int gx  = cx - 1;
            float v = 0.f;
            if ((unsigned)gy < HH && (unsigned)gx < WWD)
                v = xb[(size_t)(c0 + ci) * HW + gy * WWD + gx];
            in_lds[ci][r][cx] = v;
        }
        for (int i = tid; i < 64 * 72; i += 256) {
            int co = i / 72;
            int kk = i - co * 72;
            int ci = kk / 9;
            int k9 = kk - ci * 9;
            w_lds[ci][k9][co] = w[((size_t)(co0 + co) * CIN + (c0 + ci)) * 9 + k9];
        }
        __syncthreads();
#pragma unroll
        for (int ci = 0; ci < 8; ci++) {
#pragma unroll
            for (int ky = 0; ky < 3; ky++) {
                const float* rowp = &in_lds[ci][ky][tox];
                float4 a0 = *(const float4*)rowp;
                float4 a1 = *(const float4*)(rowp + 4);
                float2 a2 = *(const float2*)(rowp + 8);
                float in10[10] = {a0.x, a0.y, a0.z, a0.w,
                                  a1.x, a1.y, a1.z, a1.w, a2.x, a2.y};
#pragma unroll
                for (int kx = 0; kx < 3; kx++) {
                    float4 wv = *(const float4*)&w_lds[ci][ky * 3 + kx][tco];
#pragma unroll
                    for (int ox = 0; ox < 8; ox++) {
                        float iv = in10[ox + kx];
                        acc[0][ox] = fmaf(iv, wv.x, acc[0][ox]);
                        acc[1][ox] = fmaf(iv, wv.y, acc[1][ox]);
                        acc[2][ox] = fmaf(iv, wv.z, acc[2][ox]);
                        acc[3][ox] = fmaf(iv, wv.w, acc[3][ox]);
                    }
                }
            }
        }
    }

    float s = 0.f, qv = 0.f;
#pragma unroll
    for (int oc = 0; oc < 4; oc++)
#pragma unroll
        for (int ox = 0; ox < 8; ox++) { float v = acc[oc][ox]; s += v; qv = fmaf(v, v, qv); }
#pragma unroll
    for (int oc = 0; oc < 4; oc++) {
        size_t base = ((size_t)(b * CHN + co0 + tco + oc)) * HW + y * WWD + tox;
        store4v(hout + base,     acc[oc][0], acc[oc][1], acc[oc][2], acc[oc][3]);
        store4v(hout + base + 4, acc[oc][4], acc[oc][5], acc[oc][6], acc[oc][7]);
    }
    const int gsel = tco >> 5;
    atomicAdd(&sred[gsel], s);
    atomicAdd(&qred[gsel], qv);
    __syncthreads();
    if (tid < 2) {
        int grp = (co0 >> 5) + tid;
        atomicAdd(&sums[b * 8 + grp],      (double)sred[tid]);
        atomicAdd(&sums[64 + b * 8 + grp], (double)qred[tid]);
    }
}

// ===========================================================================
// GN finalize: double sums -> float stats (mainline) + double stats (fixup)
// ===========================================================================
__global__ void gn_finalize(const double* __restrict__ dsums,
                            float* __restrict__ fstats, double* __restrict__ dstats)
{
    int i = threadIdx.x;
    if (i < 64) {
        double inv = 1.0 / (double)GRP_ELEMS;
        double mu  = dsums[i] * inv;
        double ex2 = dsums[64 + i] * inv;
        double var = ex2 - mu * mu;
        double rs  = 1.0 / sqrt(var + 1e-5);
        fstats[i]      = (float)mu;
        fstats[64 + i] = (float)rs;
        dstats[i]      = mu;
        dstats[64 + i] = rs;
    }
}

__global__ void gn_finalize_all(const double* __restrict__ dsums,
                                float* __restrict__ fstats, double* __restrict__ dstats)
{
    int i = threadIdx.x;          // 0..127
    if (i < 128) {
        int head = i >> 6, j = i & 63;
        double inv = 1.0 / (double)GRP_ELEMS;
        double mu  = dsums[head * 128 + j] * inv;
        double ex2 = dsums[head * 128 + 64 + j] * inv;
        double var = ex2 - mu * mu;
        double rs  = 1.0 / sqrt(var + 1e-5);
        fstats[head * 128 + j]      = (float)mu;
        fstats[head * 128 + 64 + j] = (float)rs;
        dstats[head * 128 + j]      = mu;
        dstats[head * 128 + 64 + j] = rs;
    }
}

// ---------------------------------------------------------------------------
// GN affine -> exact GELU -> 1x1 conv (+bias). grid (64, B). (fallback paths)
// ---------------------------------------------------------------------------
template <typename HT>
__global__ __launch_bounds__(256) void gn_head(
    const HT* __restrict__ hbuf,
    const float* __restrict__ gs, const float* __restrict__ gb,
    const float* __restrict__ w2, const float* __restrict__ b2,
    const float* __restrict__ stats,
    float* __restrict__ out, int nout)
{
    __shared__ float sc[256], sh[256], w2s[2][256];
    const int b = blockIdx.y;
    const int p = blockIdx.x * 256 + threadIdx.x;
    {
        int c = threadIdx.x;
        float mu = stats[b * 8 + (c >> 5)];
        float rs = stats[64 + b * 8 + (c >> 5)];
        float s  = gs[c] * rs;
        sc[c] = s;
        sh[c] = gb[c] - mu * s;
        w2s[0][c] = w2[c];
        w2s[1][c] = (nout > 1) ? w2[256 + c] : 0.f;
    }
    __syncthreads();
    const HT* hp = hbuf + (size_t)b * CHN * HW + p;
    float a0 = 0.f, a1 = 0.f;
#pragma unroll 16
    for (int c = 0; c < 256; c++) {
        float v = ldv(hp + (size_t)c * HW);
        v = fmaf(v, sc[c], sh[c]);
        float g = 0.5f * v * (1.f + erff(v * 0.70710678118654752440f));
        a0 = fmaf(g, w2s[0][c], a0);
        a1 = fmaf(g, w2s[1][c], a1);
    }
    out[(size_t)b * nout * HW + p] = a0 + b2[0];
    if (nout > 1) out[(size_t)b * nout * HW + HW + p] = a1 + b2[1];
}

// merged two-head version: grid (64, B, 2).
__global__ __launch_bounds__(256) void gn_head_m(
    const float* __restrict__ hb1, const float* __restrict__ hb2,
    const float* __restrict__ dgs, const float* __restrict__ dgb,
    const float* __restrict__ dw2, const float* __restrict__ db2,
    const float* __restrict__ sgs, const float* __restrict__ sgb,
    const float* __restrict__ sw2, const float* __restrict__ sb2,
    const float* __restrict__ fstats, float* __restrict__ out)
{
    __shared__ float sc[256], sh[256], w2s[2][256];
    const int head = blockIdx.z;
    const float* hbuf = head ? hb2 : hb1;
    const float* gs = head ? sgs : dgs;
    const float* gb = head ? sgb : dgb;
    const float* w2 = head ? sw2 : dw2;
    const float* b2 = head ? sb2 : db2;
    const float* stats = fstats + head * 128;
    const int b = blockIdx.y;
    const int p = blockIdx.x * 256 + threadIdx.x;
    {
        int c = threadIdx.x;
        float mu = stats[b * 8 + (c >> 5)];
        float rs = stats[64 + b * 8 + (c >> 5)];
        float s  = gs[c] * rs;
        sc[c] = s;
        sh[c] = gb[c] - mu * s;
        w2s[0][c] = w2[c];
        w2s[1][c] = head ? w2[256 + c] : 0.f;
    }
    __syncthreads();
    const float* hp = hbuf + (size_t)b * CHN * HW + p;
    float a0 = 0.f, a1 = 0.f;
#pragma unroll 16
    for (int c = 0; c < 256; c++) {
        float v = hp[(size_t)c * HW];
        v = fmaf(v, sc[c], sh[c]);
        float g = 0.5f * v * (1.f + erff(v * 0.70710678118654752440f));
        a0 = fmaf(g, w2s[0][c], a0);
        a1 = fmaf(g, w2s[1][c], a1);
    }
    if (head == 0) {
        out[O_DMG + (size_t)b * HW + p] = a0 + b2[0];
    } else {
        out[O_CORN + (size_t)b * 2 * HW + p]      = a0 + b2[0];
        out[O_CORN + (size_t)b * 2 * HW + HW + p] = a1 + b2[1];
    }
}

// ---------------------------------------------------------------------------
// Decode + masked-mean accumulation + borderline flagging.
// ---------------------------------------------------------------------------
__global__ __launch_bounds__(256) void decode_kernel(
    float* __restrict__ outw, const float* __restrict__ mask,
    float* __restrict__ meanacc, float* __restrict__ cntacc,
    int* __restrict__ flagcnt, int* __restrict__ wl)
{
    const int b = blockIdx.y;
    const int p = blockIdx.x * 256 + threadIdx.x;

    float dl = outw[O_DMG + b * HW + p];
    float c0 = outw[O_CORN + (b * 2 + 0) * HW + p];
    float c1 = outw[O_CORN + (b * 2 + 1) * HW + p];

    float s0 = 1.f / (1.f + expf(-c0));
    float s1 = 1.f / (1.f + expf(-c1));
    float t0 = s0, t1 = s0 * s1;
    float e0 = fmaxf(1.f - t0, 1e-8f);
    float e1 = fmaxf(t0 - t1, 1e-8f);
    float e2 = fmaxf(t1, 1e-8f);
    float es = fmaxf(e0 + e1 + e2, 1e-8f);
    e0 /= es; e1 /= es; e2 /= es;

    float pd = 1.f / (1.f + expf(-dl));
    float q0 = fmaxf(1.f - pd, 1e-8f);
    float q1 = fmaxf(pd * e0, 1e-8f);
    float q2 = fmaxf(pd * e1, 1e-8f);
    float q3 = fmaxf(pd * e2, 1e-8f);
    float qs = fmaxf(q0 + q1 + q2 + q3, 1e-8f);
    q0 /= qs; q1 /= qs; q2 /= qs; q3 /= qs;

    outw[O_PIX + ((size_t)b * 4 + 0) * HW + p] = q0;
    outw[O_PIX + ((size_t)b * 4 + 1) * HW + p] = q1;
    outw[O_PIX + ((size_t)b * 4 + 2) * HW + p] = q2;
    outw[O_PIX + ((size_t)b * 4 + 3) * HW + p] = q3;

    int am = 0; float bv = e0;
    if (e1 > bv) { bv = e1; am = 1; }
    if (e2 > bv) { bv = e2; am = 2; }
    outw[O_LAB + b * HW + p] = (pd >= 0.5f) ? (float)(am + 1) : 0.f;

    bool flag = (fabsf(dl) < FLAG_DL);
    {
        float top1 = e0, top2 = fmaxf(e1, e2);
        if (e1 > top1) { top1 = e1; top2 = fmaxf(e0, e2); }
        if (e2 > top1) { top1 = e2; top2 = fmaxf(e0, e1); }
        if ((top1 - top2 < FLAG_GAP) && (dl > -FLAG_DL)) flag = true;
    }
    if (flag) {
        int idx = atomicAdd(flagcnt, 1);
        if (idx < WLCAP) wl[idx] = b * HW + p;
    }

    bool valid = mask[b * HW + p] > 0.5f;
    float vm = valid ? 1.f : 0.f;
    float v0 = valid ? q0 : 0.f, v1 = valid ? q1 : 0.f;
    float v2 = valid ? q2 : 0.f, v3 = valid ? q3 : 0.f;

#pragma unroll
    for (int o = 32; o; o >>= 1) {
        v0 += __shfl_down(v0, o); v1 += __shfl_down(v1, o);
        v2 += __shfl_down(v2, o); v3 += __shfl_down(v3, o);
        vm += __shfl_down(vm, o);
    }
    __shared__ float racc[5];
    if (threadIdx.x < 5) racc[threadIdx.x] = 0.f;
    __syncthreads();
    if ((threadIdx.x & 63) == 0) {
        atomicAdd(&racc[0], v0); atomicAdd(&racc[1], v1);
        atomicAdd(&racc[2], v2); atomicAdd(&racc[3], v3);
        atomicAdd(&racc[4], vm);
    }
    __syncthreads();
    if (threadIdx.x < 4) atomicAdd(&meanacc[b * 4 + threadIdx.x], racc[threadIdx.x]);
    if (threadIdx.x == 4) atomicAdd(&cntacc[b], racc[4]);
}

// ---------------------------------------------------------------------------
// fp64 fixup of pred_labels at flagged pixels. ONE pixel per block iteration.
// ---------------------------------------------------------------------------
__global__ __launch_bounds__(256) void fixup_labels(
    const float* __restrict__ x, const float* __restrict__ Wt32,
    const float* __restrict__ dgs, const float* __restrict__ dgb,
    const float* __restrict__ dw2, const float* __restrict__ db2,
    const float* __restrict__ sgs, const float* __restrict__ sgb,
    const float* __restrict__ sw2, const float* __restrict__ sb2,
    const double* __restrict__ dstat1, const double* __restrict__ dstat2,
    const int* __restrict__ wl, const int* __restrict__ wcnt,
    float* __restrict__ out)
{
    __shared__ float xp[2304];
    __shared__ double dpart[4][256];
    __shared__ double wred[3][4];

    int count = *wcnt;
    if (count > WLCAP) count = WLCAP;
    const int tid  = threadIdx.x;
    const int lane = tid & 63;
    const int wv   = tid >> 6;
    const int c4   = lane << 2;
    const int j0   = wv * 576;

    for (int pix = blockIdx.x; pix < count; pix += gridDim.x) {
        __syncthreads();
        const int pid = wl[pix];
        const int b = pid >> 14, yy = (pid >> 7) & 127, xx = pid & 127;
        for (int i = tid; i < 2304; i += 256) {
            int t = i >> 8, ci = i & 255;
            int ky = t / 3, kx = t - ky * 3;
            int gy = yy + ky - 1, gx = xx + kx - 1;
            float v = 0.f;
            if ((unsigned)gy < 128u && (unsigned)gx < 128u)
                v = x[(((size_t)b * 256 + ci) * 128 + gy) * 128 + gx];
            xp[i] = v;
        }
        __syncthreads();

        for (int head = 0; head < 2; head++) {
            const float* gs  = head ? sgs : dgs;
            const float* gb  = head ? sgb : dgb;
            const float* w2  = head ? sw2 : dw2;
            const double* st = head ? dstat2 : dstat1;
            const float* wt  = Wt32 + (size_t)head * 589824;

            double a0 = 0.0, a1 = 0.0, a2 = 0.0, a3 = 0.0;
            for (int jc = 0; jc < 576; jc += 8) {
                float4 wv4[8];
#pragma unroll
                for (int u = 0; u < 8; u++)
                    wv4[u] = *(const float4*)&wt[(size_t)(j0 + jc + u) * 256 + c4];
#pragma unroll
                for (int u = 0; u < 8; u++) {
                    double xv = (double)xp[j0 + jc + u];
                    a0 += xv * (double)wv4[u].x;
                    a1 += xv * (double)wv4[u].y;
                    a2 += xv * (double)wv4[u].z;
                    a3 += xv * (double)wv4[u].w;
                }
            }
            dpart[wv][c4]     = a0;
            dpart[wv][c4 + 1] = a1;
            dpart[wv][c4 + 2] = a2;
            dpart[wv][c4 + 3] = a3;
            __syncthreads();

            {
                const int c = tid;
                double h = dpart[0][c] + dpart[1][c] + dpart[2][c] + dpart[3][c];
                double mu = st[b * 8 + (c >> 5)];
                double rs = st[64 + b * 8 + (c >> 5)];
                double v = (h - mu) * rs * (double)gs[c] + (double)gb[c];
                double g = 0.5 * v * (1.0 + erf(v * 0.70710678118654752440));
                double r0 = g * (double)w2[c];
#pragma unroll
                for (int o = 32; o; o >>= 1) r0 += __shfl_down(r0, o);
                if (lane == 0) wred[head][wv] = r0;
                if (head == 1) {
                    double r1 = g * (double)w2[256 + c];
#pragma unroll
                    for (int o = 32; o; o >>= 1) r1 += __shfl_down(r1, o);
                    if (lane == 0) wred[2][wv] = r1;
                }
            }
            __syncthreads();
        }

        if (tid == 0) {
            double dlv = wred[0][0] + wred[0][1] + wred[0][2] + wred[0][3] + (double)db2[0];
            double c0v = wred[1][0] + wred[1][1] + wred[1][2] + wred[1][3] + (double)sb2[0];
            double c1v = wred[2][0] + wred[2][1] + wred[2][2] + wred[2][3] + (double)sb2[1];
            double s0 = 1.0 / (1.0 + exp(-c0v));
            double s1 = 1.0 / (1.0 + exp(-c1v));
            double t0 = s0, t1 = s0 * s1;
            double e0 = fmax(1.0 - t0, 1e-8);
            double e1 = fmax(t0 - t1, 1e-8);
            double e2 = fmax(t1, 1e-8);
            int am = 0; double bv = e0;
            if (e1 > bv) { bv = e1; am = 1; }
            if (e2 > bv) { bv = e2; am = 2; }
            out[O_LAB + pid] = (dlv >= 0.0) ? (float)(am + 1) : 0.f;
        }
    }
}

// ---------------------------------------------------------------------------
// Exact masked top-k mean per (b,c) via radix select. 32 blocks.
// ---------------------------------------------------------------------------
__global__ __launch_bounds__(256) void topk_kernel(
    const float* __restrict__ outw, const float* __restrict__ mask,
    const float* __restrict__ cntacc, float* __restrict__ topkout)
{
    const int b = blockIdx.x >> 2;
    const int c = blockIdx.x & 3;
    const int tid = threadIdx.x;

    __shared__ int hist[256];
    __shared__ unsigned s_prefix;
    __shared__ int s_want;
    __shared__ float s_red[4];
    __shared__ int s_redi[4];

    float cntf = cntacc[b];
    int cnt = (int)cntf;
    int k = (int)rintf(cntf * 0.2f);
    if (k < 1) k = 1;
    int kmax = cnt > 1 ? cnt : 1;
    if (k > kmax) k = kmax;

    if (tid == 0) { s_prefix = 0u; s_want = k; }

    const float* pv = outw + O_PIX + ((size_t)b * 4 + c) * HW;
    const float* pm = mask + (size_t)b * HW;

    unsigned uv[64];
#pragma unroll
    for (int j = 0; j < 64; j++) {
        int p = tid + (j << 8);
        float v = (pm[p] > 0.5f) ? pv[p] : -1.0f;
        unsigned bits = __float_as_uint(v);
        uv[j] = (bits & 0x80000000u) ? ~bits : (bits | 0x80000000u);
    }

    for (int pass = 0; pass < 4; pass++) {
        hist[tid] = 0;
        __syncthreads();
        const int shift = 24 - 8 * pass;
        const unsigned pmask = pass ? (0xFFFFFFFFu << (shift + 8)) : 0u;
        const unsigned prefix = s_prefix;
#pragma unroll
        for (int j = 0; j < 64; j++) {
            unsigned u = uv[j];
            if ((u & pmask) == prefix) atomicAdd(&hist[(u >> shift) & 255], 1);
        }
        __syncthreads();
        if (tid == 0) {
            int want = s_want;
            int bin = 255;
            while (bin > 0) {
                int h = hist[bin];
                if (want <= h) break;
                want -= h;
                bin--;
            }
            s_want = want;
            s_prefix = prefix | ((unsigned)bin << shift);
        }
        __syncthreads();
    }
    const unsigned tau = s_prefix;

    float sgt = 0.f; int cgt = 0;
#pragma unroll
    for (int j = 0; j < 64; j++) {
        unsigned u = uv[j];
        if (u > tau) {
            unsigned bits = (u & 0x80000000u) ? (u & 0x7FFFFFFFu) : ~u;
            sgt += __uint_as_float(bits);
            cgt++;
        }
    }
#pragma unroll
    for (int o = 32; o; o >>= 1) { sgt += __shfl_down(sgt, o); cgt += __shfl_down(cgt, o); }
    if ((tid & 63) == 0) { s_red[tid >> 6] = sgt; s_redi[tid >> 6] = cgt; }
    __syncthreads();
    if (tid == 0) {
        float S = s_red[0] + s_red[1] + s_red[2] + s_red[3];
        int   C = s_redi[0] + s_redi[1] + s_redi[2] + s_redi[3];
        unsigned tb = (tau & 0x80000000u) ? (tau & 0x7FFFFFFFu) : ~tau;
        float tf = __uint_as_float(tb);
        float total = S + (float)(k - C) * tf;
        topkout[b * 4 + c] = total / (float)k;
    }
}

__device__ inline void norm4(float* p)
{
    float a = fmaxf(p[0], 1e-8f), b = fmaxf(p[1], 1e-8f);
    float c = fmaxf(p[2], 1e-8f), d = fmaxf(p[3], 1e-8f);
    float s = fmaxf(a + b + c + d, 1e-8f);
    p[0] = a / s; p[1] = b / s; p[2] = c / s; p[3] = d / s;
}

__global__ void final_kernel(const float* __restrict__ meanacc,
                             const float* __restrict__ cntacc,
                             const float* __restrict__ topkv,
                             float* __restrict__ outw)
{
    int b = threadIdx.x;
    if (b >= 8) return;
    float cnt = cntacc[b];
    bool zero = (cnt == 0.f);
    float denom = fmaxf(cnt, 1.f);
    float m[4], t[4], a[4];
#pragma unroll
    for (int c = 0; c < 4; c++) {
        m[c] = zero ? 0.25f : meanacc[b * 4 + c] / denom;
        t[c] = zero ? 0.25f : topkv[b * 4 + c];
    }
    norm4(m); norm4(t);
#pragma unroll
    for (int c = 0; c < 4; c++) a[c] = 0.7f * m[c] + 0.3f * t[c];
    norm4(a);
    int am = 0; float bv = a[0];
#pragma unroll
    for (int c = 1; c < 4; c++) if (a[c] > bv) { bv = a[c]; am = c; }
#pragma unroll
    for (int c = 0; c < 4; c++) {
        outw[O_MEAN + b * 4 + c] = m[c];
        outw[O_TOPK + b * 4 + c] = t[c];
        outw[O_AGG  + b * 4 + c] = a[c];
    }
    outw[O_ALAB + b] = (float)am;
}

// ---------------------------------------------------------------------------
extern "C" void kernel_launch(void* const* d_in, const int* in_sizes, int n_in,
                              void* d_out, int out_size, void* d_ws, size_t ws_size,
                              hipStream_t stream)
{
    (void)in_sizes; (void)n_in; (void)out_size;
    const float* x    = (const float*)d_in[0];
    const float* mask = (const float*)d_in[1];
    const float* dw1  = (const float*)d_in[2];
    const float* dgs  = (const float*)d_in[3];
    const float* dgb  = (const float*)d_in[4];
    const float* dw2  = (const float*)d_in[5];
    const float* db2  = (const float*)d_in[6];
    const float* sw1  = (const float*)d_in[7];
    const float* sgs  = (const float*)d_in[8];
    const float* sgb  = (const float*)d_in[9];
    const float* sw2  = (const float*)d_in[10];
    const float* sb2  = (const float*)d_in[11];
    float* out = (float*)d_out;

    char* wsb = (char*)d_ws;
    double* dsum1  = (double*)(wsb + BO_DSUM1);
    double* dsum2  = (double*)(wsb + BO_DSUM2);
    float*  fstat1 = (float*)(wsb + BO_FSTAT1);
    float*  fstat2 = (float*)(wsb + BO_FSTAT2);
    double* dstat1 = (double*)(wsb + BO_DSTAT1);
    double* dstat2 = (double*)(wsb + BO_DSTAT2);
    float*  meanacc = (float*)(wsb + BO_MEAN);
    float*  cntacc  = (float*)(wsb + BO_CNT);
    float*  topkv   = (float*)(wsb + BO_TOPK);
    int*    flagc   = (int*)(wsb + BO_FLAGC);
    int*    wl      = (int*)(wsb + BO_WL);

    hipMemsetAsync(d_ws, 0, MEMSET_BYTES + 8192, stream);

    dim3 pgrid(64, BB);

    if (ws_size >= NEED_B) {
        ushort* Xh   = (ushort*)(wsb + XP_OFF);
        float*  hb1  = (float*)(wsb + HB_OFF);
        ushort* Whh  = (ushort*)(wsb + WH_OFF);
        ushort* Whl  = (ushort*)(wsb + WL2_OFF);
        float*  Wt32 = (float*)(wsb + WT32_OFF);
        const ushort* zb = (const ushort*)(wsb + BO_WL);

        pack_x_f16<<<8192, 256, 0, stream>>>(x, Xh);
        transpose_w<<<2304, 256, 0, stream>>>(dw1, Whh, Whl, Wt32);
        transpose_w<<<2304, 256, 0, stream>>>(sw1, Whh + WT1_ELEMS, Whl + WT1_ELEMS,
                                              Wt32 + WT1_ELEMS);

        if (ws_size >= NEED_A) {
            // ---- 8-wave merged path: both heads + full co in one block ----
            float* hb2 = (float*)(wsb + HB2_OFF);
            conv3x3_mfma8<<<dim3(1024), 512, 0, stream>>>(
                Xh, Whh, Whl, zb, hb1, hb2, dsum1);
            gn_finalize_all<<<1, 128, 0, stream>>>(dsum1, fstat1, dstat1);
            gn_head_m<<<dim3(64, BB, 2), 256, 0, stream>>>(
                hb1, hb2, dgs, dgb, dw2, db2, sgs, sgb, sw2, sb2, fstat1, out);
        } else {
            // ---- sequential path: hb reused across heads ----
            conv3x3_mfma4<<<dim3(1024, 2), 256, 0, stream>>>(
                Xh, Whh, Whl, zb, hb1, dsum1, 0);
            gn_finalize<<<1, 64, 0, stream>>>(dsum1, fstat1, dstat1);
            gn_head<float><<<pgrid, 256, 0, stream>>>(hb1, dgs, dgb, dw2, db2,
                                                      fstat1, out + O_DMG, 1);
            conv3x3_mfma4<<<dim3(1024, 2), 256, 0, stream>>>(
                Xh, Whh, Whl, zb, hb1, dsum1, 1);
            gn_finalize<<<1, 64, 0, stream>>>(dsum2, fstat2, dstat2);
            gn_head<float><<<pgrid, 256, 0, stream>>>(hb1, sgs, sgb, sw2, sb2,
                                                      fstat2, out + O_CORN, 2);
        }

        decode_kernel<<<pgrid, 256, 0, stream>>>(out, mask, meanacc, cntacc, flagc, wl);
        fixup_labels<<<512, 256, 0, stream>>>(x, Wt32, dgs, dgb, dw2, db2,
                                              sgs, sgb, sw2, sb2,
                                              dstat1, dstat2, wl, flagc, out);
        topk_kernel<<<32, 256, 0, stream>>>(out, mask, cntacc, topkv);
        final_kernel<<<1, 64, 0, stream>>>(meanacc, cntacc, topkv, out);
    } else {
        void* hbuf = wsb + XP_OFF;
        dim3 cgrid(HH * BB, CHN / 64);
        const size_t needF32 = XP_OFF + (size_t)BB * CHN * HW * sizeof(float);
        if (ws_size >= needF32) {
            conv3x3_gn_stats<float><<<cgrid, 256, 0, stream>>>(x, dw1, (float*)hbuf, dsum1);
            gn_finalize<<<1, 64, 0, stream>>>(dsum1, fstat1, dstat1);
            gn_head<float><<<pgrid, 256, 0, stream>>>((float*)hbuf, dgs, dgb, dw2, db2,
                                                      fstat1, out + O_DMG, 1);
            conv3x3_gn_stats<float><<<cgrid, 256, 0, stream>>>(x, sw1, (float*)hbuf, dsum2);
            gn_finalize<<<1, 64, 0, stream>>>(dsum2, fstat2, dstat2);
            gn_head<float><<<pgrid, 256, 0, stream>>>((float*)hbuf, sgs, sgb, sw2, sb2,
                                                      fstat2, out + O_CORN, 2);
        } else {
            conv3x3_gn_stats<__hip_bfloat16><<<cgrid, 256, 0, stream>>>(x, dw1, (__hip_bfloat16*)hbuf, dsum1);
            gn_finalize<<<1, 64, 0, stream>>>(dsum1, fstat1, dstat1);
            gn_head<__hip_bfloat16><<<pgrid, 256, 0, stream>>>((__hip_bfloat16*)hbuf, dgs, dgb, dw2, db2,
                                                               fstat1, out + O_DMG, 1);
            conv3x3_gn_stats<__hip_bfloat16><<<cgrid, 256, 0, stream>>>(x, sw1, (__hip_bfloat16*)hbuf, dsum2);
            gn_finalize<<<1, 64, 0, stream>>>(dsum2, fstat2, dstat2);
            gn_head<__hip_bfloat16><<<pgrid, 256, 0, stream>>>((__hip_bfloat16*)hbuf, sgs, sgb, sw2, sb2,
                                                               fstat2, out + O_CORN, 2);
        }
        decode_kernel<<<pgrid, 256, 0, stream>>>(out, mask, meanacc, cntacc, flagc, wl);
        topk_kernel<<<32, 256, 0, stream>>>(out, mask, cntacc, topkv);
        final_kernel<<<1, 64, 0, stream>>>(meanacc, cntacc, topkv, out);
    }
}

// Round 5
// 1103.421 us; speedup vs baseline: 1.1501x; 1.1501x over previous
//
#include <hip/hip_runtime.h>
#include <hip/hip_bf16.h>

// ---------------------------------------------------------------------------
// Problem constants
// ---------------------------------------------------------------------------
#define BB   8
#define CIN  256
#define CHN  256
#define HH   128
#define WWD  128
#define HW   (HH * WWD)        // 16384
#define GRP_ELEMS ((size_t)32 * HW)   // 524288

// borderline-label flag thresholds (>=10 sigma incl. fp16-h quantization).
#define FLAG_DL   5e-3f
#define FLAG_GAP  2e-3f

// ws BYTE layout. First MEMSET_BYTES (+8K zero page) are zeroed each call.
#define BO_DSUM1   0        // double[128] (sum[64], sumsq[64]) head1
#define BO_DSUM2   1024     // double[128] head2 (contiguous after head1)
#define BO_FSTAT1  2048     // float[128] (mu[64], rstd[64]) head1
#define BO_FSTAT2  2560     // head2 (contiguous)
#define BO_DSTAT1  3072     // double[128] head1
#define BO_DSTAT2  4096     // head2 (contiguous)
#define BO_MEAN    5120     // float[32]
#define BO_CNT     5248     // float[8]
#define BO_TOPK    5280     // float[32]
#define BO_FLAGC   5408     // int (worklist counter)
#define MEMSET_BYTES 8192
#define BO_WL      8192     // int[32768] worklist (first 8KB doubles as conv
                            // zero page: conv runs before decode writes wl)
#define WLCAP      32768

// MFMA-path big buffers (bytes). h is fp16 now (halves conv-write + gn-read).
#define XP_OFF    139264ull
#define XP_BYTES  67108864ull                  // 8*128*8*128*32 fp16 (ushort)
#define HB_OFF    (XP_OFF + XP_BYTES)
#define HB_BYTES  67108864ull                  // 8*256*16384 fp16
#define WH_OFF    (HB_OFF + HB_BYTES)
#define WT1_ELEMS 589824                       // per-head Whh/Whl ushorts; also Wt32 floats/head
#define WH2_BYTES 2359296ull                   // 2 heads * 9*8*256*32 fp16
#define WL2_OFF   (WH_OFF + WH2_BYTES)
#define WT32_OFF  (WL2_OFF + WH2_BYTES)
#define WT32_BYTES 4718592ull                  // 2 heads * 9*256*256 fp32
#define HB2_OFF   (WT32_OFF + WT32_BYTES)
#define NEED_B    (WT32_OFF + WT32_BYTES)      // sequential-conv path
#define NEED_A    (HB2_OFF + HB_BYTES)         // merged-conv path (hb2 live)

// d_out flat offsets (outputs concatenated in return order, all float)
#define O_DMG   0
#define O_CORN  131072
#define O_PIX   393216
#define O_LAB   917504
#define O_MEAN  1048576
#define O_TOPK  1048608
#define O_AGG   1048640
#define O_ALAB  1048672

typedef __attribute__((ext_vector_type(8))) _Float16 f16x8;
typedef __attribute__((ext_vector_type(4))) float f32x4;

__device__ inline ushort f2h(float f) {
    _Float16 h = (_Float16)f;
    union { _Float16 h; ushort u; } c; c.h = h; return c.u;
}
__device__ inline float h2f(ushort u) {
    union { ushort u; _Float16 h; } c; c.u = u; return (float)c.h;
}

__device__ inline void store4v(float* p, float a, float b, float c, float d) {
    *(float4*)p = make_float4(a, b, c, d);
}
__device__ inline void store4v(__hip_bfloat16* p, float a, float b, float c, float d) {
    p[0] = __float2bfloat16(a); p[1] = __float2bfloat16(b);
    p[2] = __float2bfloat16(c); p[3] = __float2bfloat16(d);
}
__device__ inline void store4v(ushort* p, float a, float b, float c, float d) {
    ushort t[4] = {f2h(a), f2h(b), f2h(c), f2h(d)};
    *(uint2*)p = *(uint2*)t;
}
__device__ inline float ldv(const float* p) { return *p; }
__device__ inline float ldv(const __hip_bfloat16* p) { return __bfloat162float(*p); }
__device__ inline float ldv(const ushort* p) { return h2f(*p); }

// ===========================================================================
// MFMA PATH (fp16, 2-product: h = fp16(x) * (wh + wl))
// ===========================================================================

// Pack x [b][ci][y][x] fp32 -> Xh [b][y][cc][x][ci32] fp16. grid 8192.
__global__ __launch_bounds__(256) void pack_x_f16(
    const float* __restrict__ x, ushort* __restrict__ Xh)
{
    int bid = blockIdx.x;
    int cc = bid & 7;
    int y  = (bid >> 3) & 127;
    int b  = bid >> 10;
    __shared__ ushort tile[32][137];
    const int tid = threadIdx.x;
    for (int i = tid; i < 1024; i += 256) {
        int ci = i >> 5;            // 0..31
        int x4 = (i & 31) << 2;     // 0..124
        float4 v = *(const float4*)&x[(((size_t)b * 256 + cc * 32 + ci) * 128 + y) * 128 + x4];
        tile[ci][x4 + 0] = f2h(v.x);
        tile[ci][x4 + 1] = f2h(v.y);
        tile[ci][x4 + 2] = f2h(v.z);
        tile[ci][x4 + 3] = f2h(v.w);
    }
    __syncthreads();
    ushort* dst = Xh + ((((size_t)b * 128 + y) * 8 + cc) << 12);
    for (int i = tid; i < 512; i += 256) {
        int xx  = i >> 2;
        int ci0 = (i & 3) << 3;
        ushort tmp[8];
#pragma unroll
        for (int j = 0; j < 8; j++) tmp[j] = tile[ci0 + j][xx];
        *(uint4*)&dst[i << 3] = *(uint4*)tmp;
    }
}

// w [co][ci][3][3] fp32 -> Whh/Whl fp16 hi/lo, SWIZZLED into MFMA B-fragment
// order. Wt32 [tap][ci][co] fp32 for the fp64 fixup (LDS-transposed).
__global__ __launch_bounds__(256) void transpose_w(
    const float* __restrict__ w, ushort* __restrict__ Whh,
    ushort* __restrict__ Whl, float* __restrict__ Wt32)
{
    __shared__ float lt[8][33];
    int idx = blockIdx.x * 256 + threadIdx.x;   // < 589824
    int tap = idx >> 16;
    int rem = idx & 65535;
    int cc  = rem >> 13;
    int co  = (rem >> 5) & 255;
    int ci5 = rem & 31;
    int ci  = cc * 32 + ci5;
    float v = w[((size_t)co * 256 + ci) * 9 + tap];
    ushort h = f2h(v);
    int sidx = (((tap * 8 + cc) * 16 + (co >> 4)) << 9)
             + (((co & 15) + ((ci5 >> 3) << 4)) << 3) + (ci5 & 7);
    Whh[sidx] = h;
    Whl[sidx] = f2h(v - h2f(h));
    lt[threadIdx.x >> 5][ci5] = v;
    __syncthreads();
    int co_base = (blockIdx.x * 8) & 255;
    int ci5w = threadIdx.x >> 3;
    int j    = threadIdx.x & 7;
    Wt32[((size_t)tap * 256 + cc * 32 + ci5w) * 256 + co_base + j] = lt[j][ci5w];
}

// ---------------------------------------------------------------------------
// global_load_lds helpers (direct HBM/L2 -> LDS DMA, 16B per lane)
// ---------------------------------------------------------------------------
__device__ __forceinline__ void gld16(const void* g, void* l)
{
    __builtin_amdgcn_global_load_lds(
        (const __attribute__((address_space(1))) void*)g,
        (__attribute__((address_space(3))) void*)l, 16, 0, 0);
}

// Stage one B slice (tap,cc) for 128 couts: 8 KB hi + 8 KB lo, 4 wave-insts.
__device__ __forceinline__ void issue_b_slice(
    const ushort* __restrict__ Whh, const ushort* __restrict__ Whl,
    ushort* dst, int u, int co0, int tid, int wb)
{
    const int su  = u / 3;               // step index (ky*8+cc)
    const int kxu = u - su * 3;
    const int tap = ((su >> 3) * 3) + kxu;
    const int cc  = su & 7;
    const size_t sbase = ((size_t)((tap * 8 + cc) * 16 + (co0 >> 4)) << 9);
    const ushort* s0 = Whh + sbase;
    const ushort* s1 = Whl + sbase;
#pragma unroll
    for (int k = 0; k < 2; k++)
        gld16(s0 + (k * 256 + tid) * 8, dst + (size_t)(k * 256 + wb) * 8);
#pragma unroll
    for (int k = 0; k < 2; k++)
        gld16(s1 + (k * 256 + tid) * 8, dst + 4096 + (size_t)(k * 256 + wb) * 8);
}

// Stage one A tile (row, cc): 128 xg x 32 ci fp16 = 8 KB, 2 wave-insts.
// Linear LDS dest; bank-conflict swizzle applied on the GLOBAL source address
// here and on the ds_read offset in the compute loop (rule #21).
__device__ __forceinline__ void issue_a_slice(
    const ushort* __restrict__ Xh, const ushort* __restrict__ zb,
    ushort* dst, int b, int y, int sn, int tid, int wb)
{
    const int kyn = sn >> 3, ccn = sn & 7;
    const int rown = y + kyn - 1;
    const bool rv = (unsigned)rown < 128u;
    const ushort* base = rv ? (Xh + ((((size_t)b * 128 + rown) * 8 + ccn) << 12)) : zb;
#pragma unroll
    for (int k = 0; k < 2; k++) {
        int idx = k * 256 + tid;
        int xi  = (idx + 4) >> 2;                  // 1..128
        int q   = (idx & 3) ^ ((xi >> 1) & 3);     // source-side swizzle
        int off = rv ? ((xi - 1) * 32 + q * 8) : (idx * 8);
        gld16(base + off, dst + 32 + (size_t)(k * 256 + wb) * 8);
    }
}

// Conv3x3 via 16x16x32 fp16 MFMA, 2 products (a*bh + a*bl).
// 72-phase pipeline: B dbuf per kx-slice (depth 1), A dbuf per (ky,cc) step
// (depth 3), all staging via global_load_lds; counted vmcnt (6/6/4).
// PROVEN R3 structure (3 blocks/CU): MERGED=1 grid (1024,4), head = by>>1,
// co0 = (by&1)<<7. Output is fp16 (ushort) now.
template <int MERGED>
__global__ __launch_bounds__(256, 3) void conv3x3_mfma(
    const ushort* __restrict__ Xh, const ushort* __restrict__ Whh,
    const ushort* __restrict__ Whl, const ushort* __restrict__ zb,
    ushort* __restrict__ hb1, ushort* __restrict__ hb2,
    double* __restrict__ sums, int headfix)
{
    __shared__ ushort a_lds[2][4160];   // [buf][row(130) * 32], 64 B rows
    __shared__ ushort b_lds[2][8192];   // [buf][hi 4096 | lo 4096]
    __shared__ float sred[8];

    const int bxr = blockIdx.x;
    const int y   = bxr >> 3;           // XCD swizzle: b = bxr&7, y = bxr>>3
    const int b   = bxr & 7;
    const int by  = blockIdx.y;
    const int head = MERGED ? (by >> 1) : headfix;
    const int co0  = MERGED ? ((by & 1) << 7) : (by << 7);
    const ushort* WhhH = Whh + head * WT1_ELEMS;
    const ushort* WhlH = Whl + head * WT1_ELEMS;
    ushort* hout = head ? hb2 : hb1;
    double* sumsH = sums + head * 128;

    const int tid  = threadIdx.x;
    const int lane = tid & 63;
    const int wb   = tid & 192;          // wave base (uniform per wave)
    const int wv   = tid >> 6;
    const int m = lane & 15;
    const int q = lane >> 4;
    const int wpx = (wv & 1) << 6;
    const int wco = (wv >> 1) << 6;
    const int g0  = wco >> 4;

    if (tid < 8) sred[tid] = 0.f;
    // zero halo rows (xi=0,129) of both A buffers: 4 rows x 64 B
    if (tid < 16) {
        int tg = tid >> 2, p4 = tid & 3;
        ushort* r = &a_lds[tg >> 1][(tg & 1) ? (129 * 32) : 0];
        *(uint4*)(r + p4 * 8) = make_uint4(0u, 0u, 0u, 0u);
    }

    f32x4 acc[4][4];
#pragma unroll
    for (int f = 0; f < 4; f++)
#pragma unroll
        for (int g = 0; g < 4; g++) acc[f][g] = (f32x4){0.f, 0.f, 0.f, 0.f};

    // prologue: A(0) -> buf0, B(0) -> buf0; drain LDS writes (halo zero/sred)
    issue_a_slice(Xh, zb, a_lds[0], b, y, 0, tid, wb);
    issue_b_slice(WhhH, WhlH, b_lds[0], 0, co0, tid, wb);
    asm volatile("s_waitcnt lgkmcnt(0)" ::: "memory");

    for (int s = 0; s < 24; s++) {
        const ushort* acur = a_lds[s & 1];
#pragma unroll
        for (int kx = 0; kx < 3; kx++) {
            const int t = 3 * s + kx;
            asm volatile("" ::: "memory");
            __builtin_amdgcn_s_barrier();           // TOP: write-safety
            {   // prefetch B(t+1) (dummy wrap at tail keeps vmcnt uniform)
                int u = t + 1;
                int ub = u & 1;
                if (u > 71) u = 71;
                issue_b_slice(WhhH, WhlH, b_lds[ub], u, co0, tid, wb);
            }
            if (kx == 0) {                          // prefetch A(s+1)
                int sn = s + 1;
                int ab = sn & 1;
                if (sn > 23) sn = 23;
                issue_a_slice(Xh, zb, a_lds[ab], b, y, sn, tid, wb);
            }
            // counted waits: in-flight = {B(t+1)=4 [, A(s+1)=2]}
            if (kx == 2) asm volatile("s_waitcnt vmcnt(4)" ::: "memory");
            else         asm volatile("s_waitcnt vmcnt(6)" ::: "memory");
            __builtin_amdgcn_s_barrier();           // MID: read-safety
            asm volatile("" ::: "memory");

            const ushort* bb = b_lds[t & 1];
            f16x8 ah[4], bh[4], bl[4];
#pragma unroll
            for (int f = 0; f < 4; f++) {
                int row = wpx + f * 16 + kx + m;
                ah[f] = *(const f16x8*)(acur + row * 32
                        + ((q ^ ((row >> 1) & 3)) << 3));   // read-side swizzle
            }
#pragma unroll
            for (int g = 0; g < 4; g++) {
                int off = ((g0 + g) << 9) + (lane << 3);
                bh[g] = *(const f16x8*)&bb[off];
                bl[g] = *(const f16x8*)&bb[4096 + off];
            }
            __builtin_amdgcn_s_setprio(1);
#pragma unroll
            for (int f = 0; f < 4; f++)
#pragma unroll
                for (int g = 0; g < 4; g++)
                    acc[f][g] = __builtin_amdgcn_mfma_f32_16x16x32_f16(ah[f], bh[g], acc[f][g], 0, 0, 0);
#pragma unroll
            for (int f = 0; f < 4; f++)
#pragma unroll
                for (int g = 0; g < 4; g++)
                    acc[f][g] = __builtin_amdgcn_mfma_f32_16x16x32_f16(ah[f], bl[g], acc[f][g], 0, 0, 0);
            __builtin_amdgcn_s_setprio(0);
        }
    }

    float s0 = 0.f, q0 = 0.f, s1 = 0.f, q1 = 0.f;
#pragma unroll
    for (int f = 0; f < 4; f++) {
#pragma unroll
        for (int g = 0; g < 4; g++) {
            f32x4 v = acc[f][g];
            float a = v.x + v.y + v.z + v.w;
            float qq = v.x * v.x + v.y * v.y + v.z * v.z + v.w * v.w;
            if (g < 2) { s0 += a; q0 += qq; } else { s1 += a; q1 += qq; }
            int px = wpx + f * 16 + q * 4;
            int co = co0 + wco + g * 16 + m;
            store4v(&hout[((size_t)(b * 256 + co) * 128 + y) * 128 + px],
                    v.x, v.y, v.z, v.w);
        }
    }
    int gl = wco >> 5;
    atomicAdd(&sred[gl],     s0);
    atomicAdd(&sred[gl + 1], s1);
    atomicAdd(&sred[4 + gl],     q0);
    atomicAdd(&sred[4 + gl + 1], q1);
    __syncthreads();
    if (tid < 4) atomicAdd(&sumsH[b * 8 + (co0 >> 5) + tid], (double)sred[tid]);
    else if (tid < 8) atomicAdd(&sumsH[64 + b * 8 + (co0 >> 5) + tid - 4], (double)sred[tid]);
}

// ===========================================================================
// fp32 fallback conv (kept for safety; not expected to run)
// ===========================================================================
template <typename HT>
__global__ __launch_bounds__(256) void conv3x3_gn_stats(
    const float* __restrict__ x, const float* __restrict__ w,
    HT* __restrict__ hout, double* __restrict__ sums)
{
    __shared__ float in_lds[8][3][132];
    __shared__ float w_lds[8][9][68];
    __shared__ float sred[2], qred[2];

    const int bx  = blockIdx.x;
    const int y   = bx & (HH - 1);
    const int b   = bx >> 7;
    const int co0 = blockIdx.y << 6;
    const int tid = threadIdx.x;
    if (tid < 2) { sred[tid] = 0.f; qred[tid] = 0.f; }
    const int tco = (tid & 15) << 2;
    const int tox = (tid >> 4) << 3;

    float acc[4][8];
#pragma unroll
    for (int i = 0; i < 4; i++)
#pragma unroll
        for (int j = 0; j < 8; j++) acc[i][j] = 0.f;

    const float* xb = x + (size_t)b * CIN * HW;
    for (int c0 = 0; c0 < CIN; c0 += 8) {
        __syncthreads();
        for (int i = tid; i < 8 * 3 * 130; i += 256) {
            int ci  = i / 390;
            int rem = i - ci * 390;
            int r   = rem / 130;
            int cx  = rem - r * 130;
            int gy  = y + r - 1;
            int gx  = cx - 1;
            float v = 0.f;
            if ((unsigned)gy < HH && (unsigned)gx < WWD)
                v = xb[(size_t)(c0 + ci) * HW + gy * WWD + gx];
            in_lds[ci][r][cx] = v;
        }
        for (int i = tid; i < 64 * 72; i += 256) {
            int co = i / 72;
            int kk = i - co * 72;
            int ci = kk / 9;
            int k9 = kk - ci * 9;
            w_lds[ci][k9][co] = w[((size_t)(co0 + co) * CIN + (c0 + ci)) * 9 + k9];
        }
        __syncthreads();
#pragma unroll
        for (int ci = 0; ci < 8; ci++) {
#pragma unroll
            for (int ky = 0; ky < 3; ky++) {
                const float* rowp = &in_lds[ci][ky][tox];
                float4 a0 = *(const float4*)rowp;
                float4 a1 = *(const float4*)(rowp + 4);
                float2 a2 = *(const float2*)(rowp + 8);
                float in10[10] = {a0.x, a0.y, a0.z, a0.w,
                                  a1.x, a1.y, a1.z, a1.w, a2.x, a2.y};
#pragma unroll
                for (int kx = 0; kx < 3; kx++) {
                    float4 wv = *(const float4*)&w_lds[ci][ky * 3 + kx][tco];
#pragma unroll
                    for (int ox = 0; ox < 8; ox++) {
                        float iv = in10[ox + kx];
                        acc[0][ox] = fmaf(iv, wv.x, acc[0][ox]);
                        acc[1][ox] = fmaf(iv, wv.y, acc[1][ox]);
                        acc[2][ox] = fmaf(iv, wv.z, acc[2][ox]);
                        acc[3][ox] = fmaf(iv, wv.w, acc[3][ox]);
                    }
                }
            }
        }
    }

    float s = 0.f, qv = 0.f;
#pragma unroll
    for (int oc = 0; oc < 4; oc++)
#pragma unroll
        for (int ox = 0; ox < 8; ox++) { float v = acc[oc][ox]; s += v; qv = fmaf(v, v, qv); }
#pragma unroll
    for (int oc = 0; oc < 4; oc++) {
        size_t base = ((size_t)(b * CHN + co0 + tco + oc)) * HW + y * WWD + tox;
        store4v(hout + base,     acc[oc][0], acc[oc][1], acc[oc][2], acc[oc][3]);
        store4v(hout + base + 4, acc[oc][4], acc[oc][5], acc[oc][6], acc[oc][7]);
    }
    const int gsel = tco >> 5;
    atomicAdd(&sred[gsel], s);
    atomicAdd(&qred[gsel], qv);
    __syncthreads();
    if (tid < 2) {
        int grp = (co0 >> 5) + tid;
        atomicAdd(&sums[b * 8 + grp],      (double)sred[tid]);
        atomicAdd(&sums[64 + b * 8 + grp], (double)qred[tid]);
    }
}

// ===========================================================================
// GN finalize: double sums -> float stats (mainline) + double stats (fixup)
// ===========================================================================
__global__ void gn_finalize(const double* __restrict__ dsums,
                            float* __restrict__ fstats, double* __restrict__ dstats)
{
    int i = threadIdx.x;
    if (i < 64) {
        double inv = 1.0 / (double)GRP_ELEMS;
        double mu  = dsums[i] * inv;
        double ex2 = dsums[64 + i] * inv;
        double var = ex2 - mu * mu;
        double rs  = 1.0 / sqrt(var + 1e-5);
        fstats[i]      = (float)mu;
        fstats[64 + i] = (float)rs;
        dstats[i]      = mu;
        dstats[64 + i] = rs;
    }
}

__global__ void gn_finalize_all(const double* __restrict__ dsums,
                                float* __restrict__ fstats, double* __restrict__ dstats)
{
    int i = threadIdx.x;          // 0..127
    if (i < 128) {
        int head = i >> 6, j = i & 63;
        double inv = 1.0 / (double)GRP_ELEMS;
        double mu  = dsums[head * 128 + j] * inv;
        double ex2 = dsums[head * 128 + 64 + j] * inv;
        double var = ex2 - mu * mu;
        double rs  = 1.0 / sqrt(var + 1e-5);
        fstats[head * 128 + j]      = (float)mu;
        fstats[head * 128 + 64 + j] = (float)rs;
        dstats[head * 128 + j]      = mu;
        dstats[head * 128 + 64 + j] = rs;
    }
}

// ---------------------------------------------------------------------------
// GN affine -> exact GELU -> 1x1 conv (+bias). grid (64, B). (fallback paths)
// ---------------------------------------------------------------------------
template <typename HT>
__global__ __launch_bounds__(256) void gn_head(
    const HT* __restrict__ hbuf,
    const float* __restrict__ gs, const float* __restrict__ gb,
    const float* __restrict__ w2, const float* __restrict__ b2,
    const float* __restrict__ stats,
    float* __restrict__ out, int nout)
{
    __shared__ float sc[256], sh[256], w2s[2][256];
    const int b = blockIdx.y;
    const int p = blockIdx.x * 256 + threadIdx.x;
    {
        int c = threadIdx.x;
        float mu = stats[b * 8 + (c >> 5)];
        float rs = stats[64 + b * 8 + (c >> 5)];
        float s  = gs[c] * rs;
        sc[c] = s;
        sh[c] = gb[c] - mu * s;
        w2s[0][c] = w2[c];
        w2s[1][c] = (nout > 1) ? w2[256 + c] : 0.f;
    }
    __syncthreads();
    const HT* hp = hbuf + (size_t)b * CHN * HW + p;
    float a0 = 0.f, a1 = 0.f;
#pragma unroll 16
    for (int c = 0; c < 256; c++) {
        float v = ldv(hp + (size_t)c * HW);
        v = fmaf(v, sc[c], sh[c]);
        float g = 0.5f * v * (1.f + erff(v * 0.70710678118654752440f));
        a0 = fmaf(g, w2s[0][c], a0);
        a1 = fmaf(g, w2s[1][c], a1);
    }
    out[(size_t)b * nout * HW + p] = a0 + b2[0];
    if (nout > 1) out[(size_t)b * nout * HW + HW + p] = a1 + b2[1];
}

// merged two-head fp16-h version: 2 px per thread. grid (32, B, 2).
__global__ __launch_bounds__(256) void gn_head_m(
    const ushort* __restrict__ hb1, const ushort* __restrict__ hb2,
    const float* __restrict__ dgs, const float* __restrict__ dgb,
    const float* __restrict__ dw2, const float* __restrict__ db2,
    const float* __restrict__ sgs, const float* __restrict__ sgb,
    const float* __restrict__ sw2, const float* __restrict__ sb2,
    const float* __restrict__ fstats, float* __restrict__ out)
{
    __shared__ float sc[256], sh[256], w2s[2][256];
    const int head = blockIdx.z;
    const ushort* hbuf = head ? hb2 : hb1;
    const float* gs = head ? sgs : dgs;
    const float* gb = head ? sgb : dgb;
    const float* w2 = head ? sw2 : dw2;
    const float* b2 = head ? sb2 : db2;
    const float* stats = fstats + head * 128;
    const int b = blockIdx.y;
    const int p = (blockIdx.x * 256 + threadIdx.x) * 2;
    {
        int c = threadIdx.x;
        float mu = stats[b * 8 + (c >> 5)];
        float rs = stats[64 + b * 8 + (c >> 5)];
        float s  = gs[c] * rs;
        sc[c] = s;
        sh[c] = gb[c] - mu * s;
        w2s[0][c] = w2[c];
        w2s[1][c] = head ? w2[256 + c] : 0.f;
    }
    __syncthreads();
    const ushort* hp = hbuf + (size_t)b * CHN * HW + p;
    float a0 = 0.f, a1 = 0.f, c0 = 0.f, c1 = 0.f;
#pragma unroll 8
    for (int c = 0; c < 256; c++) {
        uint u = *(const uint*)(hp + (size_t)c * HW);
        float v0 = fmaf(h2f((ushort)(u & 0xffffu)), sc[c], sh[c]);
        float v1 = fmaf(h2f((ushort)(u >> 16)),     sc[c], sh[c]);
        float g0 = 0.5f * v0 * (1.f + erff(v0 * 0.70710678118654752440f));
        float g1 = 0.5f * v1 * (1.f + erff(v1 * 0.70710678118654752440f));
        a0 = fmaf(g0, w2s[0][c], a0);
        c0 = fmaf(g1, w2s[0][c], c0);
        a1 = fmaf(g0, w2s[1][c], a1);
        c1 = fmaf(g1, w2s[1][c], c1);
    }
    if (head == 0) {
        out[O_DMG + (size_t)b * HW + p]     = a0 + b2[0];
        out[O_DMG + (size_t)b * HW + p + 1] = c0 + b2[0];
    } else {
        out[O_CORN + (size_t)b * 2 * HW + p]          = a0 + b2[0];
        out[O_CORN + (size_t)b * 2 * HW + p + 1]      = c0 + b2[0];
        out[O_CORN + (size_t)b * 2 * HW + HW + p]     = a1 + b2[1];
        out[O_CORN + (size_t)b * 2 * HW + HW + p + 1] = c1 + b2[1];
    }
}

// ---------------------------------------------------------------------------
// Decode + masked-mean accumulation + borderline flagging.
// ---------------------------------------------------------------------------
__global__ __launch_bounds__(256) void decode_kernel(
    float* __restrict__ outw, const float* __restrict__ mask,
    float* __restrict__ meanacc, float* __restrict__ cntacc,
    int* __restrict__ flagcnt, int* __restrict__ wl)
{
    const int b = blockIdx.y;
    const int p = blockIdx.x * 256 + threadIdx.x;

    float dl = outw[O_DMG + b * HW + p];
    float c0 = outw[O_CORN + (b * 2 + 0) * HW + p];
    float c1 = outw[O_CORN + (b * 2 + 1) * HW + p];

    float s0 = 1.f / (1.f + expf(-c0));
    float s1 = 1.f / (1.f + expf(-c1));
    float t0 = s0, t1 = s0 * s1;
    float e0 = fmaxf(1.f - t0, 1e-8f);
    float e1 = fmaxf(t0 - t1, 1e-8f);
    float e2 = fmaxf(t1, 1e-8f);
    float es = fmaxf(e0 + e1 + e2, 1e-8f);
    e0 /= es; e1 /= es; e2 /= es;

    float pd = 1.f / (1.f + expf(-dl));
    float q0 = fmaxf(1.f - pd, 1e-8f);
    float q1 = fmaxf(pd * e0, 1e-8f);
    float q2 = fmaxf(pd * e1, 1e-8f);
    float q3 = fmaxf(pd * e2, 1e-8f);
    float qs = fmaxf(q0 + q1 + q2 + q3, 1e-8f);
    q0 /= qs; q1 /= qs; q2 /= qs; q3 /= qs;

    outw[O_PIX + ((size_t)b * 4 + 0) * HW + p] = q0;
    outw[O_PIX + ((size_t)b * 4 + 1) * HW + p] = q1;
    outw[O_PIX + ((size_t)b * 4 + 2) * HW + p] = q2;
    outw[O_PIX + ((size_t)b * 4 + 3) * HW + p] = q3;

    int am = 0; float bv = e0;
    if (e1 > bv) { bv = e1; am = 1; }
    if (e2 > bv) { bv = e2; am = 2; }
    outw[O_LAB + b * HW + p] = (pd >= 0.5f) ? (float)(am + 1) : 0.f;

    bool flag = (fabsf(dl) < FLAG_DL);
    {
        float top1 = e0, top2 = fmaxf(e1, e2);
        if (e1 > top1) { top1 = e1; top2 = fmaxf(e0, e2); }
        if (e2 > top1) { top1 = e2; top2 = fmaxf(e0, e1); }
        if ((top1 - top2 < FLAG_GAP) && (dl > -FLAG_DL)) flag = true;
    }
    if (flag) {
        int idx = atomicAdd(flagcnt, 1);
        if (idx < WLCAP) wl[idx] = b * HW + p;
    }

    bool valid = mask[b * HW + p] > 0.5f;
    float vm = valid ? 1.f : 0.f;
    float v0 = valid ? q0 : 0.f, v1 = valid ? q1 : 0.f;
    float v2 = valid ? q2 : 0.f, v3 = valid ? q3 : 0.f;

#pragma unroll
    for (int o = 32; o; o >>= 1) {
        v0 += __shfl_down(v0, o); v1 += __shfl_down(v1, o);
        v2 += __shfl_down(v2, o); v3 += __shfl_down(v3, o);
        vm += __shfl_down(vm, o);
    }
    __shared__ float racc[5];
    if (threadIdx.x < 5) racc[threadIdx.x] = 0.f;
    __syncthreads();
    if ((threadIdx.x & 63) == 0) {
        atomicAdd(&racc[0], v0); atomicAdd(&racc[1], v1);
        atomicAdd(&racc[2], v2); atomicAdd(&racc[3], v3);
        atomicAdd(&racc[4], vm);
    }
    __syncthreads();
    if (threadIdx.x < 4) atomicAdd(&meanacc[b * 4 + threadIdx.x], racc[threadIdx.x]);
    if (threadIdx.x == 4) atomicAdd(&cntacc[b], racc[4]);
}

// ---------------------------------------------------------------------------
// fp64 fixup of pred_labels at flagged pixels. BATCHED: FIXP pixels share one
// streaming pass over Wt32 (W-traffic per pixel / FIXP). grid 512, block 256.
// ---------------------------------------------------------------------------
#define FIXP 6
__global__ __launch_bounds__(256) void fixup_labels(
    const float* __restrict__ x, const float* __restrict__ Wt32,
    const float* __restrict__ dgs, const float* __restrict__ dgb,
    const float* __restrict__ dw2, const float* __restrict__ db2,
    const float* __restrict__ sgs, const float* __restrict__ sgb,
    const float* __restrict__ sw2, const float* __restrict__ sb2,
    const double* __restrict__ dstat1, const double* __restrict__ dstat2,
    const int* __restrict__ wl, const int* __restrict__ wcnt,
    float* __restrict__ out)
{
    __shared__ float xp[FIXP][2304];    // per-pixel patches
    __shared__ double dpart[4][256];    // per-wave partial h[c] (one px at a time)
    __shared__ double wred[FIXP][3][4]; // [px][logit][wave]

    int count = *wcnt;
    if (count > WLCAP) count = WLCAP;
    const int tid  = threadIdx.x;
    const int lane = tid & 63;
    const int wv   = tid >> 6;
    const int c4   = lane << 2;         // this lane's first cout
    const int j0   = wv * 576;

    for (int base = blockIdx.x * FIXP; base < count; base += gridDim.x * FIXP) {
        int npx = count - base;
        if (npx > FIXP) npx = FIXP;
        __syncthreads();   // protect xp/dpart reuse across iterations
        for (int i = tid; i < npx * 2304; i += 256) {
            int px = i / 2304, j = i - px * 2304;
            int t = j >> 8, ci = j & 255;
            int ky = t / 3, kx = t - ky * 3;
            int pid = wl[base + px];
            int b = pid >> 14, yy = (pid >> 7) & 127, xx = pid & 127;
            int gy = yy + ky - 1, gx = xx + kx - 1;
            float v = 0.f;
            if ((unsigned)gy < 128u && (unsigned)gx < 128u)
                v = x[(((size_t)b * 256 + ci) * 128 + gy) * 128 + gx];
            xp[px][j] = v;
        }
        __syncthreads();

        for (int head = 0; head < 2; head++) {
            const float* gs  = head ? sgs : dgs;
            const float* gb  = head ? sgb : dgb;
            const float* w2  = head ? sw2 : dw2;
            const double* st = head ? dstat2 : dstat1;
            const float* wt  = Wt32 + (size_t)head * 589824;

            double acc[FIXP][4];
#pragma unroll
            for (int px = 0; px < FIXP; px++)
#pragma unroll
                for (int g = 0; g < 4; g++) acc[px][g] = 0.0;

            for (int jc = 0; jc < 576; jc += 8) {
                float4 wv4[8];
#pragma unroll
                for (int u = 0; u < 8; u++)
                    wv4[u] = *(const float4*)&wt[(size_t)(j0 + jc + u) * 256 + c4];
#pragma unroll
                for (int u = 0; u < 8; u++) {
#pragma unroll
                    for (int px = 0; px < FIXP; px++) {
                        double xv = (double)xp[px][j0 + jc + u];
                        acc[px][0] += xv * (double)wv4[u].x;
                        acc[px][1] += xv * (double)wv4[u].y;
                        acc[px][2] += xv * (double)wv4[u].z;
                        acc[px][3] += xv * (double)wv4[u].w;
                    }
                }
            }

#pragma unroll
            for (int px = 0; px < FIXP; px++) {
                if (px < npx) {            // npx is block-uniform: syncs safe
                    dpart[wv][c4]     = acc[px][0];
                    dpart[wv][c4 + 1] = acc[px][1];
                    dpart[wv][c4 + 2] = acc[px][2];
                    dpart[wv][c4 + 3] = acc[px][3];
                    __syncthreads();
                    {
                        const int c = tid;
                        int pid = wl[base + px];
                        int b = pid >> 14;
                        double h = dpart[0][c] + dpart[1][c] + dpart[2][c] + dpart[3][c];
                        double mu = st[b * 8 + (c >> 5)];
                        double rs = st[64 + b * 8 + (c >> 5)];
                        double v = (h - mu) * rs * (double)gs[c] + (double)gb[c];
                        double g = 0.5 * v * (1.0 + erf(v * 0.70710678118654752440));
                        double r0 = g * (double)w2[c];
#pragma unroll
                        for (int o = 32; o; o >>= 1) r0 += __shfl_down(r0, o);
                        if (lane == 0) wred[px][head][wv] = r0;
                        if (head == 1) {
                            double r1 = g * (double)w2[256 + c];
#pragma unroll
                            for (int o = 32; o; o >>= 1) r1 += __shfl_down(r1, o);
                            if (lane == 0) wred[px][2][wv] = r1;
                        }
                    }
                    __syncthreads();
                }
            }
        }

        if (tid < npx) {
            const int pid = wl[base + tid];
            double dlv = wred[tid][0][0] + wred[tid][0][1] + wred[tid][0][2]
                       + wred[tid][0][3] + (double)db2[0];
            double c0v = wred[tid][1][0] + wred[tid][1][1] + wred[tid][1][2]
                       + wred[tid][1][3] + (double)sb2[0];
            double c1v = wred[tid][2][0] + wred[tid][2][1] + wred[tid][2][2]
                       + wred[tid][2][3] + (double)sb2[1];
            double s0 = 1.0 / (1.0 + exp(-c0v));
            double s1 = 1.0 / (1.0 + exp(-c1v));
            double t0 = s0, t1 = s0 * s1;
            double e0 = fmax(1.0 - t0, 1e-8);
            double e1 = fmax(t0 - t1, 1e-8);
            double e2 = fmax(t1, 1e-8);
            int am = 0; double bv = e0;
            if (e1 > bv) { bv = e1; am = 1; }
            if (e2 > bv) { bv = e2; am = 2; }
            out[O_LAB + pid] = (dlv >= 0.0) ? (float)(am + 1) : 0.f;
        }
    }
}

// ---------------------------------------------------------------------------
// Exact masked top-k mean per (b,c) via radix select. 32 blocks.
// ---------------------------------------------------------------------------
__global__ __launch_bounds__(256) void topk_kernel(
    const float* __restrict__ outw, const float* __restrict__ mask,
    const float* __restrict__ cntacc, float* __restrict__ topkout)
{
    const int b = blockIdx.x >> 2;
    const int c = blockIdx.x & 3;
    const int tid = threadIdx.x;

    __shared__ int hist[256];
    __shared__ unsigned s_prefix;
    __shared__ int s_want;
    __shared__ float s_red[4];
    __shared__ int s_redi[4];

    float cntf = cntacc[b];
    int cnt = (int)cntf;
    int k = (int)rintf(cntf * 0.2f);
    if (k < 1) k = 1;
    int kmax = cnt > 1 ? cnt : 1;
    if (k > kmax) k = kmax;

    if (tid == 0) { s_prefix = 0u; s_want = k; }

    const float* pv = outw + O_PIX + ((size_t)b * 4 + c) * HW;
    const float* pm = mask + (size_t)b * HW;

    unsigned uv[64];
#pragma unroll
    for (int j = 0; j < 64; j++) {
        int p = tid + (j << 8);
        float v = (pm[p] > 0.5f) ? pv[p] : -1.0f;
        unsigned bits = __float_as_uint(v);
        uv[j] = (bits & 0x80000000u) ? ~bits : (bits | 0x80000000u);
    }

    for (int pass = 0; pass < 4; pass++) {
        hist[tid] = 0;
        __syncthreads();
        const int shift = 24 - 8 * pass;
        const unsigned pmask = pass ? (0xFFFFFFFFu << (shift + 8)) : 0u;
        const unsigned prefix = s_prefix;
#pragma unroll
        for (int j = 0; j < 64; j++) {
            unsigned u = uv[j];
            if ((u & pmask) == prefix) atomicAdd(&hist[(u >> shift) & 255], 1);
        }
        __syncthreads();
        if (tid == 0) {
            int want = s_want;
            int bin = 255;
            while (bin > 0) {
                int h = hist[bin];
                if (want <= h) break;
                want -= h;
                bin--;
            }
            s_want = want;
            s_prefix = prefix | ((unsigned)bin << shift);
        }
        __syncthreads();
    }
    const unsigned tau = s_prefix;

    float sgt = 0.f; int cgt = 0;
#pragma unroll
    for (int j = 0; j < 64; j++) {
        unsigned u = uv[j];
        if (u > tau) {
            unsigned bits = (u & 0x80000000u) ? (u & 0x7FFFFFFFu) : ~u;
            sgt += __uint_as_float(bits);
            cgt++;
        }
    }
#pragma unroll
    for (int o = 32; o; o >>= 1) { sgt += __shfl_down(sgt, o); cgt += __shfl_down(cgt, o); }
    if ((tid & 63) == 0) { s_red[tid >> 6] = sgt; s_redi[tid >> 6] = cgt; }
    __syncthreads();
    if (tid == 0) {
        float S = s_red[0] + s_red[1] + s_red[2] + s_red[3];
        int   C = s_redi[0] + s_redi[1] + s_redi[2] + s_redi[3];
        unsigned tb = (tau & 0x80000000u) ? (tau & 0x7FFFFFFFu) : ~tau;
        float tf = __uint_as_float(tb);
        float total = S + (float)(k - C) * tf;
        topkout[b * 4 + c] = total / (float)k;
    }
}

__device__ inline void norm4(float* p)
{
    float a = fmaxf(p[0], 1e-8f), b = fmaxf(p[1], 1e-8f);
    float c = fmaxf(p[2], 1e-8f), d = fmaxf(p[3], 1e-8f);
    float s = fmaxf(a + b + c + d, 1e-8f);
    p[0] = a / s; p[1] = b / s; p[2] = c / s; p[3] = d / s;
}

__global__ void final_kernel(const float* __restrict__ meanacc,
                             const float* __restrict__ cntacc,
                             const float* __restrict__ topkv,
                             float* __restrict__ outw)
{
    int b = threadIdx.x;
    if (b >= 8) return;
    float cnt = cntacc[b];
    bool zero = (cnt == 0.f);
    float denom = fmaxf(cnt, 1.f);
    float m[4], t[4], a[4];
#pragma unroll
    for (int c = 0; c < 4; c++) {
        m[c] = zero ? 0.25f : meanacc[b * 4 + c] / denom;
        t[c] = zero ? 0.25f : topkv[b * 4 + c];
    }
    norm4(m); norm4(t);
#pragma unroll
    for (int c = 0; c < 4; c++) a[c] = 0.7f * m[c] + 0.3f * t[c];
    norm4(a);
    int am = 0; float bv = a[0];
#pragma unroll
    for (int c = 1; c < 4; c++) if (a[c] > bv) { bv = a[c]; am = c; }
#pragma unroll
    for (int c = 0; c < 4; c++) {
        outw[O_MEAN + b * 4 + c] = m[c];
        outw[O_TOPK + b * 4 + c] = t[c];
        outw[O_AGG  + b * 4 + c] = a[c];
    }
    outw[O_ALAB + b] = (float)am;
}

// ---------------------------------------------------------------------------
extern "C" void kernel_launch(void* const* d_in, const int* in_sizes, int n_in,
                              void* d_out, int out_size, void* d_ws, size_t ws_size,
                              hipStream_t stream)
{
    (void)in_sizes; (void)n_in; (void)out_size;
    const float* x    = (const float*)d_in[0];
    const float* mask = (const float*)d_in[1];
    const float* dw1  = (const float*)d_in[2];
    const float* dgs  = (const float*)d_in[3];
    const float* dgb  = (const float*)d_in[4];
    const float* dw2  = (const float*)d_in[5];
    const float* db2  = (const float*)d_in[6];
    const float* sw1  = (const float*)d_in[7];
    const float* sgs  = (const float*)d_in[8];
    const float* sgb  = (const float*)d_in[9];
    const float* sw2  = (const float*)d_in[10];
    const float* sb2  = (const float*)d_in[11];
    float* out = (float*)d_out;

    char* wsb = (char*)d_ws;
    double* dsum1  = (double*)(wsb + BO_DSUM1);
    double* dsum2  = (double*)(wsb + BO_DSUM2);
    float*  fstat1 = (float*)(wsb + BO_FSTAT1);
    float*  fstat2 = (float*)(wsb + BO_FSTAT2);
    double* dstat1 = (double*)(wsb + BO_DSTAT1);
    double* dstat2 = (double*)(wsb + BO_DSTAT2);
    float*  meanacc = (float*)(wsb + BO_MEAN);
    float*  cntacc  = (float*)(wsb + BO_CNT);
    float*  topkv   = (float*)(wsb + BO_TOPK);
    int*    flagc   = (int*)(wsb + BO_FLAGC);
    int*    wl      = (int*)(wsb + BO_WL);

    // zero stat buffers + the first 8KB of wl (conv zero page; decode writes
    // wl only after both convs have completed on this stream)
    hipMemsetAsync(d_ws, 0, MEMSET_BYTES + 8192, stream);

    dim3 pgrid(64, BB);

    if (ws_size >= NEED_B) {
        ushort* Xh   = (ushort*)(wsb + XP_OFF);
        ushort* hb1  = (ushort*)(wsb + HB_OFF);
        ushort* Whh  = (ushort*)(wsb + WH_OFF);
        ushort* Whl  = (ushort*)(wsb + WL2_OFF);
        float*  Wt32 = (float*)(wsb + WT32_OFF);
        const ushort* zb = (const ushort*)(wsb + BO_WL);

        pack_x_f16<<<8192, 256, 0, stream>>>(x, Xh);
        transpose_w<<<2304, 256, 0, stream>>>(dw1, Whh, Whl, Wt32);
        transpose_w<<<2304, 256, 0, stream>>>(sw1, Whh + WT1_ELEMS, Whl + WT1_ELEMS,
                                              Wt32 + WT1_ELEMS);

        if (ws_size >= NEED_A) {
            // ---- merged path: both heads in one conv dispatch (R3 proven) ----
            ushort* hb2 = (ushort*)(wsb + HB2_OFF);
            conv3x3_mfma<1><<<dim3(1024, 4), 256, 0, stream>>>(
                Xh, Whh, Whl, zb, hb1, hb2, dsum1, 0);
            gn_finalize_all<<<1, 128, 0, stream>>>(dsum1, fstat1, dstat1);
            gn_head_m<<<dim3(32, BB, 2), 256, 0, stream>>>(
                hb1, hb2, dgs, dgb, dw2, db2, sgs, sgb, sw2, sb2, fstat1, out);
        } else {
            // ---- sequential path: hb reused across heads ----
            conv3x3_mfma<0><<<dim3(1024, 2), 256, 0, stream>>>(
                Xh, Whh, Whl, zb, hb1, hb1, dsum1, 0);
            gn_finalize<<<1, 64, 0, stream>>>(dsum1, fstat1, dstat1);
            gn_head<ushort><<<pgrid, 256, 0, stream>>>(hb1, dgs, dgb, dw2, db2,
                                                       fstat1, out + O_DMG, 1);
            conv3x3_mfma<0><<<dim3(1024, 2), 256, 0, stream>>>(
                Xh, Whh, Whl, zb, hb1, hb1, dsum1, 1);
            gn_finalize<<<1, 64, 0, stream>>>(dsum2, fstat2, dstat2);
            gn_head<ushort><<<pgrid, 256, 0, stream>>>(hb1, sgs, sgb, sw2, sb2,
                                                       fstat2, out + O_CORN, 2);
        }

        decode_kernel<<<pgrid, 256, 0, stream>>>(out, mask, meanacc, cntacc, flagc, wl);
        fixup_labels<<<512, 256, 0, stream>>>(x, Wt32, dgs, dgb, dw2, db2,
                                              sgs, sgb, sw2, sb2,
                                              dstat1, dstat2, wl, flagc, out);
        topk_kernel<<<32, 256, 0, stream>>>(out, mask, cntacc, topkv);
        final_kernel<<<1, 64, 0, stream>>>(meanacc, cntacc, topkv, out);
    } else {
        void* hbuf = wsb + XP_OFF;
        dim3 cgrid(HH * BB, CHN / 64);
        const size_t needF32 = XP_OFF + (size_t)BB * CHN * HW * sizeof(float);
        if (ws_size >= needF32) {
            conv3x3_gn_stats<float><<<cgrid, 256, 0, stream>>>(x, dw1, (float*)hbuf, dsum1);
            gn_finalize<<<1, 64, 0, stream>>>(dsum1, fstat1, dstat1);
            gn_head<float><<<pgrid, 256, 0, stream>>>((float*)hbuf, dgs, dgb, dw2, db2,
                                                      fstat1, out + O_DMG, 1);
            conv3x3_gn_stats<float><<<cgrid, 256, 0, stream>>>(x, sw1, (float*)hbuf, dsum2);
            gn_finalize<<<1, 64, 0, stream>>>(dsum2, fstat2, dstat2);
            gn_head<float><<<pgrid, 256, 0, stream>>>((float*)hbuf, sgs, sgb, sw2, sb2,
                                                      fstat2, out + O_CORN, 2);
        } else {
            conv3x3_gn_stats<__hip_bfloat16><<<cgrid, 256, 0, stream>>>(x, dw1, (__hip_bfloat16*)hbuf, dsum1);
            gn_finalize<<<1, 64, 0, stream>>>(dsum1, fstat1, dstat1);
            gn_head<__hip_bfloat16><<<pgrid, 256, 0, stream>>>((__hip_bfloat16*)hbuf, dgs, dgb, dw2, db2,
                                                               fstat1, out + O_DMG, 1);
            conv3x3_gn_stats<__hip_bfloat16><<<cgrid, 256, 0, stream>>>(x, sw1, (__hip_bfloat16*)hbuf, dsum2);
            gn_finalize<<<1, 64, 0, stream>>>(dsum2, fstat2, dstat2);
            gn_head<__hip_bfloat16><<<pgrid, 256, 0, stream>>>((__hip_bfloat16*)hbuf, sgs, sgb, sw2, sb2,
                                                               fstat2, out + O_CORN, 2);
        }
        decode_kernel<<<pgrid, 256, 0, stream>>>(out, mask, meanacc, cntacc, flagc, wl);
        topk_kernel<<<32, 256, 0, stream>>>(out, mask, cntacc, topkv);
        final_kernel<<<1, 64, 0, stream>>>(meanacc, cntacc, topkv, out);
    }
}